// Round 10
// baseline (292.801 us; speedup 1.0000x reference)
//
#include <hip/hip_runtime.h>
#include <hip/hip_bf16.h>
#include <math.h>

#define B_  4
#define T_  2048
#define C_  1024
#define NH_ 16
#define HD_ 64

using bf16 = __hip_bfloat16;
typedef __attribute__((ext_vector_type(8))) short bf16x8;   // 8 bf16 (4 VGPRs)
typedef __attribute__((ext_vector_type(4))) short bf16x4;   // 4 bf16 (2 VGPRs)
typedef __attribute__((ext_vector_type(4))) float f32x4;

__device__ __forceinline__ bf16 f2b(float f){ return __float2bfloat16(f); }

// fast round-to-nearest-even fp32->bf16 (exact for all finite values; no NaN path)
__device__ __forceinline__ short f2bs(float f){
  union { float f; unsigned u; } x; x.f = f;
  x.u += 0x7FFFu + ((x.u >> 16) & 1u);
  return (short)(x.u >> 16);
}

// packed fp32x2 -> bf16x2 (v_cvt_pk_bf16_f32 on gfx950)
__device__ __forceinline__ bf16x4 pack_bf16x4(float a, float b, float c, float d){
  union { bf16x4 v; __hip_bfloat162 h[2]; } u;
  u.h[0] = __float22bfloat162_rn(make_float2(a, b));
  u.h[1] = __float22bfloat162_rn(make_float2(c, d));
  return u.v;
}

// raw v_exp_f32: exp2 with no ocml range-fixup wrapper.
__device__ __forceinline__ float fexp2(float x){
  float r; asm("v_exp_f32 %0, %1" : "=v"(r) : "v"(x)); return r;
}

__device__ __forceinline__ void async_load16(const bf16* g, bf16* l){
  __builtin_amdgcn_global_load_lds((const __attribute__((address_space(1))) unsigned int*)g,
                                   (__attribute__((address_space(3))) unsigned int*)l,
                                   16, 0, 0);
}

// 0.125 (1/sqrt(64)) * log2(e): softmax runs in exp2 domain
#define QSCALE 0.18033688011112042f

// ---------------- fused prep: x f32->bf16 (blocks 0..8191) + weight transposes ----------------
__global__ __launch_bounds__(256) void k_prep(const float* __restrict__ x, bf16* __restrict__ xb, int n,
                                              const float* __restrict__ in0, bf16* __restrict__ out0,
                                              const float* __restrict__ in1, bf16* __restrict__ out1){
  __shared__ float t[32][33];
  int b = blockIdx.x;
  if (b < 8192){
    int i = (b * 256 + threadIdx.x) * 4;
    if (i < n){
      float4 f = *(const float4*)(x + i);
      ushort4 u;
      u.x = (unsigned short)f2bs(f.x);
      u.y = (unsigned short)f2bs(f.y);
      u.z = (unsigned short)f2bs(f.z);
      u.w = (unsigned short)f2bs(f.w);
      *(ushort4*)(xb + i) = u;
    }
    return;
  }
  b -= 8192;
  const float* in; bf16* out; int Cc, bx, by;
  if (b < 3072){ in = in0; out = out0; Cc = 3*C_; bx = (b % 96)*32; by = (b / 96)*32; }
  else { b -= 3072; in = in1; out = out1; Cc = C_; bx = (b & 31)*32; by = (b >> 5)*32; }
  const int R = C_;
  int lx = threadIdx.x & 31, ly = threadIdx.x >> 5;
  #pragma unroll
  for (int s = 0; s < 4; s++){
    int k = by + ly + s*8;
    t[ly + s*8][lx] = in[(size_t)k * Cc + bx + lx];
  }
  __syncthreads();
  #pragma unroll
  for (int s = 0; s < 4; s++){
    int n2 = bx + ly + s*8;
    out[(size_t)n2 * R + by + lx] = f2b(t[lx][ly + s*8]);
  }
}

// ------- GEMM: 256x128 tile, per-wave 128x64, ring-of-3 slots, counted-vmcnt -------
// ROUND 20: round-9 showed extra blocks/CU don't help (3 blk ≡ 2 blk, both pipes <55%) —
// the LDS port is the saturated shared resource (48 KB LDS traffic per block-stage for
// 2.1 MFLOP = 32 B/KFLOP; ~9 MB/CU ≈ 30 µs port floor for gemm0). Fix: per-wave output
// tile 128x64 (acc[8][4], 4 waves, BM=256 BN=128) -> per-wave reads 12 KB/stage for
// 0.52 MFLOP = 24 B/KFLOP; total LDS traffic -25%; block count halves.
// Schedule per 32-K stage t (VERBATIM round-9, 6 loads/stage):
//   s_waitcnt vmcnt(6)  [vmcnt(0) at t==S-1]  // retires stage t; t+1 stays in flight
//   s_barrier + sched_barrier(0)
//   ds_read bfv[4]; stage t+2 -> slot (t+2)%3 (4 A + 2 B loads); two halves of
//   {af[4] reads + setprio(1) 16 MFMA setprio(0)}
// Ledger: outstanding at top = stages {t,t+1} = 12; vmcnt(6) retires exactly stage t.
// Slot (t+2)%3 = slot of stage t-1, fully consumed before this barrier => safe.
// LDS 72 KB static (3 x (16 KB A + 8 KB B)) -> 2 blocks/CU (round-9: >saturation anyway).
// Swizzle per [rows][32] slot: VERBATIM (chunk q of row r at pos q^((r>>1)&3), global
// source pre-swizzled, reads quad^((l15>>1)&3); conflicts == 0).
// Epilogues: row-completing store order (WRITE == ideal), extended to i<8.
// MODE 0: scatter Q(*QSCALE)/K (d^=(t&7)*8) and Vt (t^=(d&7)*8). MODE 1: fp32 row-major.
template<int MODE>
__global__ __launch_bounds__(256) void k_gemm10(
    const bf16* __restrict__ A, const bf16* __restrict__ BT,
    const float* __restrict__ bias,
    bf16* __restrict__ qo, bf16* __restrict__ ko, bf16* __restrict__ vo,
    float* __restrict__ fout,
    int M, int N, int K)
{
  __shared__ bf16 As[3][256*32];
  __shared__ bf16 Bs[3][128*32];

  const int tid  = threadIdx.x;
  const int wave = tid >> 6, lane = tid & 63;
  const int wm = wave & 1, wn = wave >> 1;          // 2M x 2N wave grid; per-wave 128x64
  const int quad = lane >> 4, l15 = lane & 15;
  const int bm = blockIdx.x * 256;
  const int bn = blockIdx.y * 128;

  // staging: A 1024 chunks (4/thread), B 512 chunks (2/thread), 16B each
  const bf16* gA[4]; int lofsA[4];
  #pragma unroll
  for (int s = 0; s < 4; s++){
    const int c = tid + s*256;
    const int r = c >> 2, p = (c & 3) ^ ((r >> 1) & 3);
    gA[s] = A + (size_t)(bm + r)*K + p*8;
    lofsA[s] = c*8;
  }
  const bf16* gB[2]; int lofsB[2];
  #pragma unroll
  for (int s = 0; s < 2; s++){
    const int c = tid + s*256;
    const int r = c >> 2, p = (c & 3) ^ ((r >> 1) & 3);
    gB[s] = BT + (size_t)(bn + r)*K + p*8;
    lofsB[s] = c*8;
  }
  const int fsw = (l15 >> 1) & 3;      // fragment-read chunk XOR

  f32x4 acc[8][4] = {};
  const int S = K >> 5;                // number of 32-K stages

  // prologue: stages 0,1 -> slots 0,1 (FIFO: stage 0's 6 loads are oldest)
  #pragma unroll
  for (int t = 0; t < 2; t++){
    #pragma unroll
    for (int s = 0; s < 4; s++) async_load16(gA[s] + t*32, &As[t][0] + lofsA[s]);
    #pragma unroll
    for (int s = 0; s < 2; s++) async_load16(gB[s] + t*32, &Bs[t][0] + lofsB[s]);
  }

  int slot = 0, sslot = 2;
  for (int t = 0; t < S; t++){
    if (t < S - 1) asm volatile("s_waitcnt vmcnt(6)" ::: "memory");
    else           asm volatile("s_waitcnt vmcnt(0)" ::: "memory");
    __builtin_amdgcn_s_barrier();
    __builtin_amdgcn_sched_barrier(0);

    const bf16* as = &As[slot][0];
    const bf16* bs = &Bs[slot][0];
    bf16x8 bfv[4];
    #pragma unroll
    for (int j = 0; j < 4; j++)
      bfv[j] = *reinterpret_cast<const bf16x8*>(bs + (wn*64 + j*16 + l15)*32 + ((quad ^ fsw) << 3));

    if (t + 2 < S){
      const int ko2 = (t + 2) * 32;
      #pragma unroll
      for (int s = 0; s < 4; s++) async_load16(gA[s] + ko2, &As[sslot][0] + lofsA[s]);
      #pragma unroll
      for (int s = 0; s < 2; s++) async_load16(gB[s] + ko2, &Bs[sslot][0] + lofsB[s]);
    }

    #pragma unroll
    for (int h = 0; h < 2; h++){
      bf16x8 af[4];
      #pragma unroll
      for (int i = 0; i < 4; i++)
        af[i] = *reinterpret_cast<const bf16x8*>(as + (wm*128 + (h*4+i)*16 + l15)*32 + ((quad ^ fsw) << 3));
      __builtin_amdgcn_s_setprio(1);
      #pragma unroll
      for (int i = 0; i < 4; i++)
        #pragma unroll
        for (int j = 0; j < 4; j++)
          acc[h*4+i][j] = __builtin_amdgcn_mfma_f32_16x16x32_bf16(af[i], bfv[j], acc[h*4+i][j], 0, 0, 0);
      __builtin_amdgcn_s_setprio(0);
    }

    slot  = (slot  == 2) ? 0 : slot  + 1;
    sslot = (sslot == 2) ? 0 : sslot + 1;
  }

  // epilogue: C/D layout row = quad*4 + reg, col = lane&15
  if (MODE == 0){
    const int sec = bn >> 10;
    const int bb2 = bm >> 11;
    const int tb  = (bm & (T_ - 1)) + wm*128 + quad*4;
    const int hn  = ((bn & 1023) >> 6) + wn;
    const size_t bhx = (size_t)(bb2 * NH_ + hn);
    if (sec == 2){
      #pragma unroll
      for (int j = 0; j < 4; j++){
        const int d2 = j*16 + l15;
        const float bj = bias[bn + wn*64 + j*16 + l15];
        bf16* vrow = vo + (bhx * HD_ + d2) * (size_t)T_;
        const int sw = (l15 & 7) * 8;          // kv-swizzle (d&7 == l15&7)
        #pragma unroll
        for (int i = 0; i < 8; i++){
          const int t = (tb + i*16) ^ sw;
          *reinterpret_cast<bf16x4*>(vrow + t) =
            pack_bf16x4(acc[i][j][0] + bj, acc[i][j][1] + bj,
                        acc[i][j][2] + bj, acc[i][j][3] + bj);
        }
      }
    } else {
      bf16* dst = (sec == 0) ? qo : ko;
      const float sc = (sec == 0) ? QSCALE : 1.0f;
      bf16* base = dst + bhx * T_ * HD_;
      float bj[4];
      #pragma unroll
      for (int j = 0; j < 4; j++) bj[j] = bias[bn + wn*64 + j*16 + l15];
      // row-completing order: j innermost -> full 128-B line dirty in consecutive stores
      #pragma unroll
      for (int i = 0; i < 8; i++){
        #pragma unroll
        for (int r = 0; r < 4; r++){
          const int t  = tb + i*16 + r;
          const int sw2 = (t & 7) * 8;
          bf16* prow = base + (size_t)t * HD_;
          #pragma unroll
          for (int j = 0; j < 4; j++){
            const int dq = (j*16 + l15) ^ sw2;   // d-swizzle
            short s = f2bs((acc[i][j][r] + bj[j]) * sc);
            prow[dq] = *(bf16*)&s;
          }
        }
      }
    }
  } else {
    const int n0 = bn + wn*64 + l15;
    float bj[4];
    #pragma unroll
    for (int j = 0; j < 4; j++) bj[j] = bias[n0 + j*16];
    // row-completing order: j innermost
    #pragma unroll
    for (int i = 0; i < 8; i++){
      #pragma unroll
      for (int r = 0; r < 4; r++){
        float* p0 = fout + (size_t)(bm + wm*128 + i*16 + quad*4 + r) * N + n0;
        #pragma unroll
        for (int j = 0; j < 4; j++)
          p0[j*16] = acc[i][j][r] + bj[j];
      }
    }
  }
}

// ---------------- flash attention: async dbuf K/V, Q in regs, 128-row q-tiles ----------------
// ROUND 20: UNCHANGED (control).
__global__ __launch_bounds__(256) void k_attn(
    const bf16* __restrict__ Q, const bf16* __restrict__ Kg,
    const bf16* __restrict__ Vt, bf16* __restrict__ Y)
{
  __shared__ bf16 Ks[2][64*64];   // [kv][d'] unpadded
  __shared__ bf16 Vs[2][64*64];   // [d][kv'] unpadded

  const int bh = blockIdx.x;
  const int bb = bh >> 4, hh = bh & 15;
  const int qt = 15 - blockIdx.y;          // 128-row q-tile, reversed dispatch
  const int tid  = threadIdx.x;
  const int wave = tid >> 6, lane = tid & 63;
  const int quad = lane >> 4, l15 = lane & 15;
  const int swz  = (l15 & 7) * 8;        // fragment-read XOR (t&7 == l15&7 everywhere used)

  const size_t baseQK = (size_t)bh * T_ * HD_;
  const size_t baseV  = (size_t)bh * HD_ * T_;

  // async staging geometry: 8 chunks of 1024B per 64x64 tile; wave w -> chunks {w, w+4}
  const int ca = wave, cb = wave + 4;
  const bf16* kg_a = Kg + baseQK + ca*512 + (size_t)lane*8;
  const bf16* kg_b = Kg + baseQK + cb*512 + (size_t)lane*8;
  const bf16* vg_a = Vt + baseV + (size_t)(ca*8 + (lane>>3)) * T_ + (lane&7)*8;
  const bf16* vg_b = Vt + baseV + (size_t)(cb*8 + (lane>>3)) * T_ + (lane&7)*8;
  bf16* kl_a0 = &Ks[0][0] + ca*512;  bf16* kl_b0 = &Ks[0][0] + cb*512;
  bf16* vl_a0 = &Vs[0][0] + ca*512;  bf16* vl_b0 = &Vs[0][0] + cb*512;

  // constant ones A-fragment (A[m][k] = (m==0)): denominator row
  bf16x4 ones_f;
  {
    short v = (l15 == 0) ? f2bs(1.0f) : (short)0;
    ones_f = (bf16x4){ v, v, v, v };
  }
  const f32x4 ZV = {0.0f, 0.0f, 0.0f, 0.0f};   // loop-invariant zero C-operand

  const int jmax = 2*qt + 1;               // kv tiles 0..jmax (diag pair at 2qt, 2qt+1)

  // Q fragments -> registers; wave covers q rows qt*128 + s*64 + wave*16 + [0,16)
  bf16x8 qf[2][2];
  #pragma unroll
  for (int s = 0; s < 2; s++){
    const int t = qt*128 + s*64 + wave*16 + l15;
    #pragma unroll
    for (int ks = 0; ks < 2; ks++){
      const int col = (ks*32 + quad*8) ^ swz;
      qf[s][ks] = *reinterpret_cast<const bf16x8*>(Q + baseQK + (size_t)t*HD_ + col);
    }
  }

  // prologue: async tile 0 -> buf 0
  async_load16(kg_a, kl_a0);  async_load16(kg_b, kl_b0);
  async_load16(vg_a, vl_a0);  async_load16(vg_b, vl_b0);

  f32x4 o[2][5] = {};           // per-subtile O^T accum; o[s][4] row0 = softmax denom

  for (int j = 0; j <= jmax; j++){
    __syncthreads();   // drains tile-j asyncs (in flight a full iter), publishes LDS

    if (j < jmax){     // issue tile j+1 into the other buffer; overlaps compute below
      const int nb = ((j+1) & 1) * 4096;
      const size_t ko = (size_t)(j+1) * 64 * HD_;
      async_load16(kg_a + ko, kl_a0 + nb);  async_load16(kg_b + ko, kl_b0 + nb);
      async_load16(vg_a + (j+1)*64, vl_a0 + nb);
      async_load16(vg_b + (j+1)*64, vl_b0 + nb);
    }

    const bf16* ksb = &Ks[j & 1][0];
    const bf16* vsb = &Vs[j & 1][0];

    // S^T = K * Q^T : tk outer, ks inner; first MFMA takes ZV (no per-tile zero-init)
    f32x4 st[2][4];
    __builtin_amdgcn_s_setprio(1);
    #pragma unroll
    for (int tk = 0; tk < 4; tk++){
      bf16x8 kf0 = *reinterpret_cast<const bf16x8*>(ksb + (tk*16 + l15)*64 + ((quad*8) ^ swz));
      bf16x8 kf1 = *reinterpret_cast<const bf16x8*>(ksb + (tk*16 + l15)*64 + ((32 + quad*8) ^ swz));
      st[0][tk] = __builtin_amdgcn_mfma_f32_16x16x32_bf16(kf0, qf[0][0], ZV, 0, 0, 0);
      st[1][tk] = __builtin_amdgcn_mfma_f32_16x16x32_bf16(kf0, qf[1][0], ZV, 0, 0, 0);
      st[0][tk] = __builtin_amdgcn_mfma_f32_16x16x32_bf16(kf1, qf[0][1], st[0][tk], 0, 0, 0);
      st[1][tk] = __builtin_amdgcn_mfma_f32_16x16x32_bf16(kf1, qf[1][1], st[1][tk], 0, 0, 0);
    }
    __builtin_amdgcn_s_setprio(0);

    // P = exp2(S) (fixed-shift softmax), pack to bf16.
    bf16x4 pf[2][4];
    #pragma unroll
    for (int s = 0; s < 2; s++){
      const int qg = qt*128 + s*64 + wave*16 + l15;
      const bool msk = s ? (j > 2*qt) : (j >= 2*qt);
      #pragma unroll
      for (int tk = 0; tk < 4; tk++){
        float e[4];
        #pragma unroll
        for (int r = 0; r < 4; r++){
          float sv = st[s][tk][r];
          if (msk){
            const int kvg = j*64 + tk*16 + quad*4 + r;
            if (kvg > qg) sv = -1e30f;     // exp2 -> 0
          }
          e[r] = fexp2(sv);
        }
        pf[s][tk] = pack_bf16x4(e[0], e[1], e[2], e[3]);
      }
    }

    // O^T += V^T * P^T ; each vf fragment feeds both q-subtiles; denom via ones-A-frag
    __builtin_amdgcn_s_setprio(1);
    #pragma unroll
    for (int td = 0; td < 4; td++){
      #pragma unroll
      for (int tk = 0; tk < 4; tk++){
        bf16x4 vf = *reinterpret_cast<const bf16x4*>(vsb + (td*16 + l15)*64 + ((tk*16 + quad*4) ^ swz));
        o[0][td] = __builtin_amdgcn_mfma_f32_16x16x16bf16_1k(vf, pf[0][tk], o[0][td], 0, 0, 0);
        o[1][td] = __builtin_amdgcn_mfma_f32_16x16x16bf16_1k(vf, pf[1][tk], o[1][td], 0, 0, 0);
      }
    }
    #pragma unroll
    for (int tk = 0; tk < 4; tk++){
      o[0][4] = __builtin_amdgcn_mfma_f32_16x16x16bf16_1k(ones_f, pf[0][tk], o[0][4], 0, 0, 0);
      o[1][4] = __builtin_amdgcn_mfma_f32_16x16x16bf16_1k(ones_f, pf[1][tk], o[1][4], 0, 0, 0);
    }
    __builtin_amdgcn_s_setprio(0);
  }

  // normalize + write Y[B*T][C], one 16-row group per wave per subtile
  #pragma unroll
  for (int s = 0; s < 2; s++){
    const float l = __shfl(o[s][4][0], l15, 64);   // quad-0 lane l15 holds q=l15 denom
    const float inv = 1.0f / l;
    const int t = qt*128 + s*64 + wave*16 + l15;
    bf16* yrow = Y + ((size_t)(bb * T_ + t)) * C_ + hh * HD_;
    #pragma unroll
    for (int td = 0; td < 4; td++){
      *reinterpret_cast<bf16x4*>(yrow + td*16 + quad*4) =
        pack_bf16x4(o[s][td][0] * inv, o[s][td][1] * inv,
                    o[s][td][2] * inv, o[s][td][3] * inv);
    }
  }
}

// ---------------- launcher ----------------

extern "C" void kernel_launch(void* const* d_in, const int* in_sizes, int n_in,
                              void* d_out, int out_size, void* d_ws, size_t ws_size,
                              hipStream_t stream) {
  const float* x     = (const float*)d_in[0];
  const float* Wqkv  = (const float*)d_in[1];
  const float* bqkv  = (const float*)d_in[2];
  const float* Wproj = (const float*)d_in[3];
  const float* bproj = (const float*)d_in[4];
  float* out = (float*)d_out;

  const size_t M = (size_t)B_ * T_;
  char* w = (char*)d_ws;
  bf16* xb     = (bf16*)w;  w += M * C_ * 2;
  bf16* WqkvT  = (bf16*)w;  w += (size_t)3 * C_ * C_ * 2;
  bf16* WprojT = (bf16*)w;  w += (size_t)C_ * C_ * 2;
  bf16* Qb     = (bf16*)w;  w += M * C_ * 2;
  bf16* Kb     = (bf16*)w;  w += M * C_ * 2;
  bf16* Vtb    = (bf16*)w;  w += M * C_ * 2;
  bf16* Yb     = (bf16*)w;  w += M * C_ * 2;

  {
    int n = (int)(M * C_);
    k_prep<<<dim3(12288), dim3(256), 0, stream>>>(x, xb, n, Wqkv, WqkvT, Wproj, WprojT);
  }
  k_gemm10<0><<<dim3(M/256, (3*C_)/128), dim3(256), 0, stream>>>(
      xb, WqkvT, bqkv, Qb, Kb, Vtb, nullptr, (int)M, 3*C_, C_);
  k_attn<<<dim3(64, 16), dim3(256), 0, stream>>>(Qb, Kb, Vtb, Yb);
  k_gemm10<1><<<dim3(M/256, C_/128), dim3(256), 0, stream>>>(
      Yb, WprojT, bproj, nullptr, nullptr, nullptr, out, (int)M, C_, C_);
}

// Round 11
// 238.708 us; speedup vs baseline: 1.2266x; 1.2266x over previous
//
#include <hip/hip_runtime.h>
#include <hip/hip_bf16.h>
#include <math.h>

#define B_  4
#define T_  2048
#define C_  1024
#define NH_ 16
#define HD_ 64

using bf16 = __hip_bfloat16;
typedef __attribute__((ext_vector_type(8))) short bf16x8;   // 8 bf16 (4 VGPRs)
typedef __attribute__((ext_vector_type(4))) short bf16x4;   // 4 bf16 (2 VGPRs)
typedef __attribute__((ext_vector_type(4))) float f32x4;

__device__ __forceinline__ bf16 f2b(float f){ return __float2bfloat16(f); }

// fast round-to-nearest-even fp32->bf16 (exact for all finite values; no NaN path)
__device__ __forceinline__ short f2bs(float f){
  union { float f; unsigned u; } x; x.f = f;
  x.u += 0x7FFFu + ((x.u >> 16) & 1u);
  return (short)(x.u >> 16);
}

// packed fp32x2 -> bf16x2 (v_cvt_pk_bf16_f32 on gfx950)
__device__ __forceinline__ bf16x4 pack_bf16x4(float a, float b, float c, float d){
  union { bf16x4 v; __hip_bfloat162 h[2]; } u;
  u.h[0] = __float22bfloat162_rn(make_float2(a, b));
  u.h[1] = __float22bfloat162_rn(make_float2(c, d));
  return u.v;
}

// raw v_exp_f32: exp2 with no ocml range-fixup wrapper.
__device__ __forceinline__ float fexp2(float x){
  float r; asm("v_exp_f32 %0, %1" : "=v"(r) : "v"(x)); return r;
}

__device__ __forceinline__ void async_load16(const bf16* g, bf16* l){
  __builtin_amdgcn_global_load_lds((const __attribute__((address_space(1))) unsigned int*)g,
                                   (__attribute__((address_space(3))) unsigned int*)l,
                                   16, 0, 0);
}

// 0.125 (1/sqrt(64)) * log2(e): softmax runs in exp2 domain
#define QSCALE 0.18033688011112042f

// ---------------- fused prep: x f32->bf16 (blocks 0..8191) + weight transposes ----------------
// ROUND 21: transpose writes were 64-B partial lines (each 128-B line of out split between
// two blocks) -> partial-line eviction + RMW write amplification (round-5-proven mechanism).
// Now each block transposes a 64-k-strip: each output row write = 32 lanes x ushort2 = one
// full 128-B line. Blocks: 8192 x-cvt, 1536 Wqkv (96 n-tiles x 16 k-strips), 512 Wproj.
__global__ __launch_bounds__(256) void k_prep(const float* __restrict__ x, bf16* __restrict__ xb, int n,
                                              const float* __restrict__ in0, bf16* __restrict__ out0,
                                              const float* __restrict__ in1, bf16* __restrict__ out1){
  __shared__ float t[64][33];
  int b = blockIdx.x;
  if (b < 8192){
    int i = (b * 256 + threadIdx.x) * 4;
    if (i < n){
      float4 f = *(const float4*)(x + i);
      ushort4 u;
      u.x = (unsigned short)f2bs(f.x);
      u.y = (unsigned short)f2bs(f.y);
      u.z = (unsigned short)f2bs(f.z);
      u.w = (unsigned short)f2bs(f.w);
      *(ushort4*)(xb + i) = u;
    }
    return;
  }
  b -= 8192;
  const float* in; bf16* out; int Cc, bx, by;
  if (b < 1536){ in = in0; out = out0; Cc = 3*C_; bx = (b % 96)*32; by = (b / 96)*64; }
  else { b -= 1536; in = in1; out = out1; Cc = C_; bx = (b & 31)*32; by = (b >> 5)*64; }
  const int R = C_;
  int lx = threadIdx.x & 31, ly = threadIdx.x >> 5;
  #pragma unroll
  for (int s = 0; s < 8; s++){
    int k = by + ly + s*8;
    t[ly + s*8][lx] = in[(size_t)k * Cc + bx + lx];
  }
  __syncthreads();
  #pragma unroll
  for (int s = 0; s < 4; s++){
    const int nl = ly + s*8;
    const int n2 = bx + nl;
    ushort2 v;
    v.x = (unsigned short)f2bs(t[2*lx    ][nl]);
    v.y = (unsigned short)f2bs(t[2*lx + 1][nl]);
    *(ushort2*)(out + (size_t)n2 * R + by + 2*lx) = v;
  }
}

// ------- GEMM: 128x128 tile, BK=64 as two k-sub-stages, counted-vmcnt phase pipeline -------
// ROUND 21: VERBATIM round-8 (best measured: 236.65 total, gemm0 67.8 us, 725->766 TF).
// Rounds 9 (ring-of-3, more TLP) and 10 (fat 128x64 waves, less LDS traffic) both proved
// the structure is at a latency/serialization equilibrium: neither more blocks nor less
// LDS traffic moves it. Do not touch without a new counter-backed theory.
template<int MODE>
__global__ __launch_bounds__(256, 2) void k_gemm8(
    const bf16* __restrict__ A, const bf16* __restrict__ BT,
    const float* __restrict__ bias,
    bf16* __restrict__ qo, bf16* __restrict__ ko, bf16* __restrict__ vo,
    float* __restrict__ fout,
    int M, int N, int K)
{
  __shared__ bf16 As[2][2][128*32];
  __shared__ bf16 Bs[2][2][128*32];

  const int tid  = threadIdx.x;
  const int wave = tid >> 6, lane = tid & 63;
  const int wm = wave & 1, wn = wave >> 1;          // 2M x 2N wave grid
  const int quad = lane >> 4, l15 = lane & 15;
  const int bm = blockIdx.x * 128;
  const int bn = blockIdx.y * 128;

  // staging: per kh sub-buffer 512 chunks of 16B; thread covers c = tid, tid+256
  const bf16* gA[2]; const bf16* gB[2]; int lofs[2];
  #pragma unroll
  for (int s = 0; s < 2; s++){
    const int c = tid + s*256;
    const int r = c >> 2, p = (c & 3) ^ ((r >> 1) & 3);
    gA[s] = A  + (size_t)(bm + r)*K + p*8;
    gB[s] = BT + (size_t)(bn + r)*K + p*8;
    lofs[s] = c*8;
  }
  const int fsw = (l15 >> 1) & 3;      // fragment-read chunk XOR

  f32x4 acc[4][4] = {};
  const int nT = K >> 6;

  // prologue: tile 0, k-halves in order k0 then k1 (FIFO: k0 = 4 oldest)
  #pragma unroll
  for (int kh = 0; kh < 2; kh++)
    #pragma unroll
    for (int s = 0; s < 2; s++){
      async_load16(gA[s] + kh*32, &As[0][kh][0] + lofs[s]);
      async_load16(gB[s] + kh*32, &Bs[0][kh][0] + lofs[s]);
    }

  for (int u = 0; u < nT; u++){
    const int d = u & 1;
    #pragma unroll
    for (int kh = 0; kh < 2; kh++){
      if (u + 1 < nT || kh == 0) asm volatile("s_waitcnt vmcnt(4)" ::: "memory");
      else                       asm volatile("s_waitcnt vmcnt(0)" ::: "memory");
      __builtin_amdgcn_s_barrier();
      __builtin_amdgcn_sched_barrier(0);

      const bf16* as = &As[d][kh][0];
      const bf16* bs = &Bs[d][kh][0];
      bf16x8 af[4], bfv[4];
      #pragma unroll
      for (int i = 0; i < 4; i++)
        af[i]  = *reinterpret_cast<const bf16x8*>(as + (wm*64 + i*16 + l15)*32 + ((quad ^ fsw) << 3));
      #pragma unroll
      for (int j = 0; j < 4; j++)
        bfv[j] = *reinterpret_cast<const bf16x8*>(bs + (wn*64 + j*16 + l15)*32 + ((quad ^ fsw) << 3));

      if (u + 1 < nT){
        const int ko2 = (u + 1)*64 + kh*32;
        #pragma unroll
        for (int s = 0; s < 2; s++){
          async_load16(gA[s] + ko2, &As[d^1][kh][0] + lofs[s]);
          async_load16(gB[s] + ko2, &Bs[d^1][kh][0] + lofs[s]);
        }
      }

      __builtin_amdgcn_s_setprio(1);
      #pragma unroll
      for (int i = 0; i < 4; i++)
        #pragma unroll
        for (int j = 0; j < 4; j++)
          acc[i][j] = __builtin_amdgcn_mfma_f32_16x16x32_bf16(af[i], bfv[j], acc[i][j], 0, 0, 0);
      __builtin_amdgcn_s_setprio(0);
    }
  }

  // epilogue: C/D layout row = quad*4 + reg, col = lane&15
  if (MODE == 0){
    const int sec = bn >> 10;
    const int bb2 = bm >> 11;
    const int tb  = (bm & (T_ - 1)) + wm*64 + quad*4;
    const int hn  = ((bn & 1023) >> 6) + wn;
    const size_t bhx = (size_t)(bb2 * NH_ + hn);
    if (sec == 2){
      #pragma unroll
      for (int j = 0; j < 4; j++){
        const int d2 = j*16 + l15;
        const float bj = bias[bn + wn*64 + j*16 + l15];
        bf16* vrow = vo + (bhx * HD_ + d2) * (size_t)T_;
        const int sw = (l15 & 7) * 8;          // kv-swizzle (d&7 == l15&7)
        #pragma unroll
        for (int i = 0; i < 4; i++){
          const int t = (tb + i*16) ^ sw;
          *reinterpret_cast<bf16x4*>(vrow + t) =
            pack_bf16x4(acc[i][j][0] + bj, acc[i][j][1] + bj,
                        acc[i][j][2] + bj, acc[i][j][3] + bj);
        }
      }
    } else {
      bf16* dst = (sec == 0) ? qo : ko;
      const float sc = (sec == 0) ? QSCALE : 1.0f;
      bf16* base = dst + bhx * T_ * HD_;
      float bj[4];
      #pragma unroll
      for (int j = 0; j < 4; j++) bj[j] = bias[bn + wn*64 + j*16 + l15];
      // row-completing order: j innermost -> full 128-B line dirty in consecutive stores
      #pragma unroll
      for (int i = 0; i < 4; i++){
        #pragma unroll
        for (int r = 0; r < 4; r++){
          const int t  = tb + i*16 + r;
          const int sw2 = (t & 7) * 8;
          bf16* prow = base + (size_t)t * HD_;
          #pragma unroll
          for (int j = 0; j < 4; j++){
            const int dq = (j*16 + l15) ^ sw2;   // d-swizzle
            short s = f2bs((acc[i][j][r] + bj[j]) * sc);
            prow[dq] = *(bf16*)&s;
          }
        }
      }
    }
  } else {
    const int n0 = bn + wn*64 + l15;
    float bj[4];
    #pragma unroll
    for (int j = 0; j < 4; j++) bj[j] = bias[n0 + j*16];
    // row-completing order: j innermost
    #pragma unroll
    for (int i = 0; i < 4; i++){
      #pragma unroll
      for (int r = 0; r < 4; r++){
        float* p0 = fout + (size_t)(bm + wm*64 + i*16 + quad*4 + r) * N + n0;
        #pragma unroll
        for (int j = 0; j < 4; j++)
          p0[j*16] = acc[i][j][r] + bj[j];
      }
    }
  }
}

// ---------------- flash attention: async dbuf K/V, Q in regs, 128-row q-tiles ----------------
// ROUND 21: peeled the last KV-iteration (j = 2qt+1). Subtile 0 is fully masked there —
// previously it still ran 8 QK MFMAs + 16 exps + 20 PV/denom MFMAs producing exact zeros.
// Peel computes subtile 1 only; main loop (j <= 2qt) drops the s=1 mask entirely and masks
// s=0 only at j == 2qt. No per-iteration branch overhead added. Numerically identical
// (skipped ops contributed +0 to o[0]).
__global__ __launch_bounds__(256) void k_attn(
    const bf16* __restrict__ Q, const bf16* __restrict__ Kg,
    const bf16* __restrict__ Vt, bf16* __restrict__ Y)
{
  __shared__ bf16 Ks[2][64*64];   // [kv][d'] unpadded
  __shared__ bf16 Vs[2][64*64];   // [d][kv'] unpadded

  const int bh = blockIdx.x;
  const int bb = bh >> 4, hh = bh & 15;
  const int qt = 15 - blockIdx.y;          // 128-row q-tile, reversed dispatch
  const int tid  = threadIdx.x;
  const int wave = tid >> 6, lane = tid & 63;
  const int quad = lane >> 4, l15 = lane & 15;
  const int swz  = (l15 & 7) * 8;        // fragment-read XOR (t&7 == l15&7 everywhere used)

  const size_t baseQK = (size_t)bh * T_ * HD_;
  const size_t baseV  = (size_t)bh * HD_ * T_;

  // async staging geometry: 8 chunks of 1024B per 64x64 tile; wave w -> chunks {w, w+4}
  const int ca = wave, cb = wave + 4;
  const bf16* kg_a = Kg + baseQK + ca*512 + (size_t)lane*8;
  const bf16* kg_b = Kg + baseQK + cb*512 + (size_t)lane*8;
  const bf16* vg_a = Vt + baseV + (size_t)(ca*8 + (lane>>3)) * T_ + (lane&7)*8;
  const bf16* vg_b = Vt + baseV + (size_t)(cb*8 + (lane>>3)) * T_ + (lane&7)*8;
  bf16* kl_a0 = &Ks[0][0] + ca*512;  bf16* kl_b0 = &Ks[0][0] + cb*512;
  bf16* vl_a0 = &Vs[0][0] + ca*512;  bf16* vl_b0 = &Vs[0][0] + cb*512;

  // constant ones A-fragment (A[m][k] = (m==0)): denominator row
  bf16x4 ones_f;
  {
    short v = (l15 == 0) ? f2bs(1.0f) : (short)0;
    ones_f = (bf16x4){ v, v, v, v };
  }
  const f32x4 ZV = {0.0f, 0.0f, 0.0f, 0.0f};   // loop-invariant zero C-operand

  // Q fragments -> registers; wave covers q rows qt*128 + s*64 + wave*16 + [0,16)
  bf16x8 qf[2][2];
  #pragma unroll
  for (int s = 0; s < 2; s++){
    const int t = qt*128 + s*64 + wave*16 + l15;
    #pragma unroll
    for (int ks = 0; ks < 2; ks++){
      const int col = (ks*32 + quad*8) ^ swz;
      qf[s][ks] = *reinterpret_cast<const bf16x8*>(Q + baseQK + (size_t)t*HD_ + col);
    }
  }

  // prologue: async tile 0 -> buf 0
  async_load16(kg_a, kl_a0);  async_load16(kg_b, kl_b0);
  async_load16(vg_a, vl_a0);  async_load16(vg_b, vl_b0);

  f32x4 o[2][5] = {};           // per-subtile O^T accum; o[s][4] row0 = softmax denom

  // ---- main loop: j = 0..2qt, both subtiles live; s=1 never masked here ----
  for (int j = 0; j <= 2*qt; j++){
    __syncthreads();   // drains tile-j asyncs (in flight a full iter), publishes LDS

    {  // stage tile j+1 (always exists: j+1 <= 2qt+1 = last tile)
      const int nb = ((j+1) & 1) * 4096;
      const size_t ko = (size_t)(j+1) * 64 * HD_;
      async_load16(kg_a + ko, kl_a0 + nb);  async_load16(kg_b + ko, kl_b0 + nb);
      async_load16(vg_a + (j+1)*64, vl_a0 + nb);
      async_load16(vg_b + (j+1)*64, vl_b0 + nb);
    }

    const bf16* ksb = &Ks[j & 1][0];
    const bf16* vsb = &Vs[j & 1][0];

    // S^T = K * Q^T : tk outer, ks inner; first MFMA takes ZV
    f32x4 st[2][4];
    __builtin_amdgcn_s_setprio(1);
    #pragma unroll
    for (int tk = 0; tk < 4; tk++){
      bf16x8 kf0 = *reinterpret_cast<const bf16x8*>(ksb + (tk*16 + l15)*64 + ((quad*8) ^ swz));
      bf16x8 kf1 = *reinterpret_cast<const bf16x8*>(ksb + (tk*16 + l15)*64 + ((32 + quad*8) ^ swz));
      st[0][tk] = __builtin_amdgcn_mfma_f32_16x16x32_bf16(kf0, qf[0][0], ZV, 0, 0, 0);
      st[1][tk] = __builtin_amdgcn_mfma_f32_16x16x32_bf16(kf0, qf[1][0], ZV, 0, 0, 0);
      st[0][tk] = __builtin_amdgcn_mfma_f32_16x16x32_bf16(kf1, qf[0][1], st[0][tk], 0, 0, 0);
      st[1][tk] = __builtin_amdgcn_mfma_f32_16x16x32_bf16(kf1, qf[1][1], st[1][tk], 0, 0, 0);
    }
    __builtin_amdgcn_s_setprio(0);

    // P = exp2(S); s=0 masked only at the diagonal tile j == 2qt
    bf16x4 pf[2][4];
    {
      const int qg = qt*128 + wave*16 + l15;
      const bool msk = (j == 2*qt);
      #pragma unroll
      for (int tk = 0; tk < 4; tk++){
        float e[4];
        #pragma unroll
        for (int r = 0; r < 4; r++){
          float sv = st[0][tk][r];
          if (msk){
            const int kvg = j*64 + tk*16 + quad*4 + r;
            if (kvg > qg) sv = -1e30f;
          }
          e[r] = fexp2(sv);
        }
        pf[0][tk] = pack_bf16x4(e[0], e[1], e[2], e[3]);
      }
    }
    #pragma unroll
    for (int tk = 0; tk < 4; tk++){
      float e[4];
      #pragma unroll
      for (int r = 0; r < 4; r++) e[r] = fexp2(st[1][tk][r]);
      pf[1][tk] = pack_bf16x4(e[0], e[1], e[2], e[3]);
    }

    // O^T += V^T * P^T ; denom via ones-A-frag
    __builtin_amdgcn_s_setprio(1);
    #pragma unroll
    for (int td = 0; td < 4; td++){
      #pragma unroll
      for (int tk = 0; tk < 4; tk++){
        bf16x4 vf = *reinterpret_cast<const bf16x4*>(vsb + (td*16 + l15)*64 + ((tk*16 + quad*4) ^ swz));
        o[0][td] = __builtin_amdgcn_mfma_f32_16x16x16bf16_1k(vf, pf[0][tk], o[0][td], 0, 0, 0);
        o[1][td] = __builtin_amdgcn_mfma_f32_16x16x16bf16_1k(vf, pf[1][tk], o[1][td], 0, 0, 0);
      }
    }
    #pragma unroll
    for (int tk = 0; tk < 4; tk++){
      o[0][4] = __builtin_amdgcn_mfma_f32_16x16x16bf16_1k(ones_f, pf[0][tk], o[0][4], 0, 0, 0);
      o[1][4] = __builtin_amdgcn_mfma_f32_16x16x16bf16_1k(ones_f, pf[1][tk], o[1][4], 0, 0, 0);
    }
    __builtin_amdgcn_s_setprio(0);
  }

  // ---- peeled last tile j = 2qt+1: subtile 1 only (subtile 0 fully masked -> zeros) ----
  {
    const int j = 2*qt + 1;
    __syncthreads();   // drains the tile staged at main-loop j == 2qt

    const bf16* ksb = &Ks[j & 1][0];
    const bf16* vsb = &Vs[j & 1][0];

    f32x4 st1[4];
    __builtin_amdgcn_s_setprio(1);
    #pragma unroll
    for (int tk = 0; tk < 4; tk++){
      bf16x8 kf0 = *reinterpret_cast<const bf16x8*>(ksb + (tk*16 + l15)*64 + ((quad*8) ^ swz));
      bf16x8 kf1 = *reinterpret_cast<const bf16x8*>(ksb + (tk*16 + l15)*64 + ((32 + quad*8) ^ swz));
      st1[tk] = __builtin_amdgcn_mfma_f32_16x16x32_bf16(kf0, qf[1][0], ZV, 0, 0, 0);
      st1[tk] = __builtin_amdgcn_mfma_f32_16x16x32_bf16(kf1, qf[1][1], st1[tk], 0, 0, 0);
    }
    __builtin_amdgcn_s_setprio(0);

    bf16x4 pf1[4];
    {
      const int qg = qt*128 + 64 + wave*16 + l15;   // subtile-1 rows; diagonal mask
      #pragma unroll
      for (int tk = 0; tk < 4; tk++){
        float e[4];
        #pragma unroll
        for (int r = 0; r < 4; r++){
          float sv = st1[tk][r];
          const int kvg = j*64 + tk*16 + quad*4 + r;
          if (kvg > qg) sv = -1e30f;
          e[r] = fexp2(sv);
        }
        pf1[tk] = pack_bf16x4(e[0], e[1], e[2], e[3]);
      }
    }

    __builtin_amdgcn_s_setprio(1);
    #pragma unroll
    for (int td = 0; td < 4; td++){
      #pragma unroll
      for (int tk = 0; tk < 4; tk++){
        bf16x4 vf = *reinterpret_cast<const bf16x4*>(vsb + (td*16 + l15)*64 + ((tk*16 + quad*4) ^ swz));
        o[1][td] = __builtin_amdgcn_mfma_f32_16x16x16bf16_1k(vf, pf1[tk], o[1][td], 0, 0, 0);
      }
    }
    #pragma unroll
    for (int tk = 0; tk < 4; tk++)
      o[1][4] = __builtin_amdgcn_mfma_f32_16x16x16bf16_1k(ones_f, pf1[tk], o[1][4], 0, 0, 0);
    __builtin_amdgcn_s_setprio(0);
  }

  // normalize + write Y[B*T][C], one 16-row group per wave per subtile
  #pragma unroll
  for (int s = 0; s < 2; s++){
    const float l = __shfl(o[s][4][0], l15, 64);   // quad-0 lane l15 holds q=l15 denom
    const float inv = 1.0f / l;
    const int t = qt*128 + s*64 + wave*16 + l15;
    bf16* yrow = Y + ((size_t)(bb * T_ + t)) * C_ + hh * HD_;
    #pragma unroll
    for (int td = 0; td < 4; td++){
      *reinterpret_cast<bf16x4*>(yrow + td*16 + quad*4) =
        pack_bf16x4(o[s][td][0] * inv, o[s][td][1] * inv,
                    o[s][td][2] * inv, o[s][td][3] * inv);
    }
  }
}

// ---------------- launcher ----------------

extern "C" void kernel_launch(void* const* d_in, const int* in_sizes, int n_in,
                              void* d_out, int out_size, void* d_ws, size_t ws_size,
                              hipStream_t stream) {
  const float* x     = (const float*)d_in[0];
  const float* Wqkv  = (const float*)d_in[1];
  const float* bqkv  = (const float*)d_in[2];
  const float* Wproj = (const float*)d_in[3];
  const float* bproj = (const float*)d_in[4];
  float* out = (float*)d_out;

  const size_t M = (size_t)B_ * T_;
  char* w = (char*)d_ws;
  bf16* xb     = (bf16*)w;  w += M * C_ * 2;
  bf16* WqkvT  = (bf16*)w;  w += (size_t)3 * C_ * C_ * 2;
  bf16* WprojT = (bf16*)w;  w += (size_t)C_ * C_ * 2;
  bf16* Qb     = (bf16*)w;  w += M * C_ * 2;
  bf16* Kb     = (bf16*)w;  w += M * C_ * 2;
  bf16* Vtb    = (bf16*)w;  w += M * C_ * 2;
  bf16* Yb     = (bf16*)w;  w += M * C_ * 2;

  {
    int n = (int)(M * C_);
    k_prep<<<dim3(10240), dim3(256), 0, stream>>>(x, xb, n, Wqkv, WqkvT, Wproj, WprojT);
  }
  k_gemm8<0><<<dim3(M/128, (3*C_)/128), dim3(256), 0, stream>>>(
      xb, WqkvT, bqkv, Qb, Kb, Vtb, nullptr, (int)M, 3*C_, C_);
  k_attn<<<dim3(64, 16), dim3(256), 0, stream>>>(Qb, Kb, Vtb, Yb);
  k_gemm8<1><<<dim3(M/128, C_/128), dim3(256), 0, stream>>>(
      Yb, WprojT, bproj, nullptr, nullptr, nullptr, out, (int)M, C_, C_);
}

// Round 12
// 236.261 us; speedup vs baseline: 1.2393x; 1.0104x over previous
//
#include <hip/hip_runtime.h>
#include <hip/hip_bf16.h>
#include <math.h>

#define B_  4
#define T_  2048
#define C_  1024
#define NH_ 16
#define HD_ 64

using bf16 = __hip_bfloat16;
typedef __attribute__((ext_vector_type(8))) short bf16x8;   // 8 bf16 (4 VGPRs)
typedef __attribute__((ext_vector_type(4))) short bf16x4;   // 4 bf16 (2 VGPRs)
typedef __attribute__((ext_vector_type(4))) float f32x4;

__device__ __forceinline__ bf16 f2b(float f){ return __float2bfloat16(f); }

// fast round-to-nearest-even fp32->bf16 (exact for all finite values; no NaN path)
__device__ __forceinline__ short f2bs(float f){
  union { float f; unsigned u; } x; x.f = f;
  x.u += 0x7FFFu + ((x.u >> 16) & 1u);
  return (short)(x.u >> 16);
}

// packed fp32x2 -> bf16x2 (v_cvt_pk_bf16_f32 on gfx950)
__device__ __forceinline__ bf16x4 pack_bf16x4(float a, float b, float c, float d){
  union { bf16x4 v; __hip_bfloat162 h[2]; } u;
  u.h[0] = __float22bfloat162_rn(make_float2(a, b));
  u.h[1] = __float22bfloat162_rn(make_float2(c, d));
  return u.v;
}

// raw v_exp_f32: exp2 with no ocml range-fixup wrapper.
__device__ __forceinline__ float fexp2(float x){
  float r; asm("v_exp_f32 %0, %1" : "=v"(r) : "v"(x)); return r;
}

__device__ __forceinline__ void async_load16(const bf16* g, bf16* l){
  __builtin_amdgcn_global_load_lds((const __attribute__((address_space(1))) unsigned int*)g,
                                   (__attribute__((address_space(3))) unsigned int*)l,
                                   16, 0, 0);
}

// 0.125 (1/sqrt(64)) * log2(e): softmax runs in exp2 domain
#define QSCALE 0.18033688011112042f

// ---------------- fused prep: x f32->bf16 (blocks 0..8191) + weight transposes ----------------
// ROUND 22: reverted to the round-8 version (32x33 tile, 12288 blocks). The round-11
// 64-strip rewrite was the prime suspect for a +2 us net regression; its theoretical
// write-amp saving (~1.3 us) didn't show. A/B: vs round-8 only attn differs now.
__global__ __launch_bounds__(256) void k_prep(const float* __restrict__ x, bf16* __restrict__ xb, int n,
                                              const float* __restrict__ in0, bf16* __restrict__ out0,
                                              const float* __restrict__ in1, bf16* __restrict__ out1){
  __shared__ float t[32][33];
  int b = blockIdx.x;
  if (b < 8192){
    int i = (b * 256 + threadIdx.x) * 4;
    if (i < n){
      float4 f = *(const float4*)(x + i);
      ushort4 u;
      u.x = (unsigned short)f2bs(f.x);
      u.y = (unsigned short)f2bs(f.y);
      u.z = (unsigned short)f2bs(f.z);
      u.w = (unsigned short)f2bs(f.w);
      *(ushort4*)(xb + i) = u;
    }
    return;
  }
  b -= 8192;
  const float* in; bf16* out; int Cc, bx, by;
  if (b < 3072){ in = in0; out = out0; Cc = 3*C_; bx = (b % 96)*32; by = (b / 96)*32; }
  else { b -= 3072; in = in1; out = out1; Cc = C_; bx = (b & 31)*32; by = (b >> 5)*32; }
  const int R = C_;
  int lx = threadIdx.x & 31, ly = threadIdx.x >> 5;
  #pragma unroll
  for (int s = 0; s < 4; s++){
    int k = by + ly + s*8;
    t[ly + s*8][lx] = in[(size_t)k * Cc + bx + lx];
  }
  __syncthreads();
  #pragma unroll
  for (int s = 0; s < 4; s++){
    int n2 = bx + ly + s*8;
    out[(size_t)n2 * R + by + lx] = f2b(t[lx][ly + s*8]);
  }
}

// ------- GEMM: 128x128 tile, BK=64 as two k-sub-stages, counted-vmcnt phase pipeline -------
// ROUND 22: VERBATIM round-8 (best measured: 236.65 total, gemm0 67.8 us).
// Rounds 9 (ring-of-3) and 10 (fat waves; confounded by 1.5-round grid tail) established
// this as a latency/serialization equilibrium. Do not touch without new counter evidence.
template<int MODE>
__global__ __launch_bounds__(256, 2) void k_gemm8(
    const bf16* __restrict__ A, const bf16* __restrict__ BT,
    const float* __restrict__ bias,
    bf16* __restrict__ qo, bf16* __restrict__ ko, bf16* __restrict__ vo,
    float* __restrict__ fout,
    int M, int N, int K)
{
  __shared__ bf16 As[2][2][128*32];
  __shared__ bf16 Bs[2][2][128*32];

  const int tid  = threadIdx.x;
  const int wave = tid >> 6, lane = tid & 63;
  const int wm = wave & 1, wn = wave >> 1;          // 2M x 2N wave grid
  const int quad = lane >> 4, l15 = lane & 15;
  const int bm = blockIdx.x * 128;
  const int bn = blockIdx.y * 128;

  // staging: per kh sub-buffer 512 chunks of 16B; thread covers c = tid, tid+256
  const bf16* gA[2]; const bf16* gB[2]; int lofs[2];
  #pragma unroll
  for (int s = 0; s < 2; s++){
    const int c = tid + s*256;
    const int r = c >> 2, p = (c & 3) ^ ((r >> 1) & 3);
    gA[s] = A  + (size_t)(bm + r)*K + p*8;
    gB[s] = BT + (size_t)(bn + r)*K + p*8;
    lofs[s] = c*8;
  }
  const int fsw = (l15 >> 1) & 3;      // fragment-read chunk XOR

  f32x4 acc[4][4] = {};
  const int nT = K >> 6;

  // prologue: tile 0, k-halves in order k0 then k1 (FIFO: k0 = 4 oldest)
  #pragma unroll
  for (int kh = 0; kh < 2; kh++)
    #pragma unroll
    for (int s = 0; s < 2; s++){
      async_load16(gA[s] + kh*32, &As[0][kh][0] + lofs[s]);
      async_load16(gB[s] + kh*32, &Bs[0][kh][0] + lofs[s]);
    }

  for (int u = 0; u < nT; u++){
    const int d = u & 1;
    #pragma unroll
    for (int kh = 0; kh < 2; kh++){
      if (u + 1 < nT || kh == 0) asm volatile("s_waitcnt vmcnt(4)" ::: "memory");
      else                       asm volatile("s_waitcnt vmcnt(0)" ::: "memory");
      __builtin_amdgcn_s_barrier();
      __builtin_amdgcn_sched_barrier(0);

      const bf16* as = &As[d][kh][0];
      const bf16* bs = &Bs[d][kh][0];
      bf16x8 af[4], bfv[4];
      #pragma unroll
      for (int i = 0; i < 4; i++)
        af[i]  = *reinterpret_cast<const bf16x8*>(as + (wm*64 + i*16 + l15)*32 + ((quad ^ fsw) << 3));
      #pragma unroll
      for (int j = 0; j < 4; j++)
        bfv[j] = *reinterpret_cast<const bf16x8*>(bs + (wn*64 + j*16 + l15)*32 + ((quad ^ fsw) << 3));

      if (u + 1 < nT){
        const int ko2 = (u + 1)*64 + kh*32;
        #pragma unroll
        for (int s = 0; s < 2; s++){
          async_load16(gA[s] + ko2, &As[d^1][kh][0] + lofs[s]);
          async_load16(gB[s] + ko2, &Bs[d^1][kh][0] + lofs[s]);
        }
      }

      __builtin_amdgcn_s_setprio(1);
      #pragma unroll
      for (int i = 0; i < 4; i++)
        #pragma unroll
        for (int j = 0; j < 4; j++)
          acc[i][j] = __builtin_amdgcn_mfma_f32_16x16x32_bf16(af[i], bfv[j], acc[i][j], 0, 0, 0);
      __builtin_amdgcn_s_setprio(0);
    }
  }

  // epilogue: C/D layout row = quad*4 + reg, col = lane&15
  if (MODE == 0){
    const int sec = bn >> 10;
    const int bb2 = bm >> 11;
    const int tb  = (bm & (T_ - 1)) + wm*64 + quad*4;
    const int hn  = ((bn & 1023) >> 6) + wn;
    const size_t bhx = (size_t)(bb2 * NH_ + hn);
    if (sec == 2){
      #pragma unroll
      for (int j = 0; j < 4; j++){
        const int d2 = j*16 + l15;
        const float bj = bias[bn + wn*64 + j*16 + l15];
        bf16* vrow = vo + (bhx * HD_ + d2) * (size_t)T_;
        const int sw = (l15 & 7) * 8;          // kv-swizzle (d&7 == l15&7)
        #pragma unroll
        for (int i = 0; i < 4; i++){
          const int t = (tb + i*16) ^ sw;
          *reinterpret_cast<bf16x4*>(vrow + t) =
            pack_bf16x4(acc[i][j][0] + bj, acc[i][j][1] + bj,
                        acc[i][j][2] + bj, acc[i][j][3] + bj);
        }
      }
    } else {
      bf16* dst = (sec == 0) ? qo : ko;
      const float sc = (sec == 0) ? QSCALE : 1.0f;
      bf16* base = dst + bhx * T_ * HD_;
      float bj[4];
      #pragma unroll
      for (int j = 0; j < 4; j++) bj[j] = bias[bn + wn*64 + j*16 + l15];
      // row-completing order: j innermost -> full 128-B line dirty in consecutive stores
      #pragma unroll
      for (int i = 0; i < 4; i++){
        #pragma unroll
        for (int r = 0; r < 4; r++){
          const int t  = tb + i*16 + r;
          const int sw2 = (t & 7) * 8;
          bf16* prow = base + (size_t)t * HD_;
          #pragma unroll
          for (int j = 0; j < 4; j++){
            const int dq = (j*16 + l15) ^ sw2;   // d-swizzle
            short s = f2bs((acc[i][j][r] + bj[j]) * sc);
            prow[dq] = *(bf16*)&s;
          }
        }
      }
    }
  } else {
    const int n0 = bn + wn*64 + l15;
    float bj[4];
    #pragma unroll
    for (int j = 0; j < 4; j++) bj[j] = bias[n0 + j*16];
    // row-completing order: j innermost
    #pragma unroll
    for (int i = 0; i < 4; i++){
      #pragma unroll
      for (int r = 0; r < 4; r++){
        float* p0 = fout + (size_t)(bm + wm*64 + i*16 + quad*4 + r) * N + n0;
        #pragma unroll
        for (int j = 0; j < 4; j++)
          p0[j*16] = acc[i][j][r] + bj[j];
      }
    }
  }
}

// ---------------- flash attention: async dbuf K/V, Q in regs, 128-row q-tiles ----------------
// ROUND 22: keeps the round-11 last-tile peel (j = 2qt+1: subtile 0 fully masked -> compute
// subtile 1 only; main loop masks s=0 only at j == 2qt). Strict work reduction vs round-8.
__global__ __launch_bounds__(256) void k_attn(
    const bf16* __restrict__ Q, const bf16* __restrict__ Kg,
    const bf16* __restrict__ Vt, bf16* __restrict__ Y)
{
  __shared__ bf16 Ks[2][64*64];   // [kv][d'] unpadded
  __shared__ bf16 Vs[2][64*64];   // [d][kv'] unpadded

  const int bh = blockIdx.x;
  const int bb = bh >> 4, hh = bh & 15;
  const int qt = 15 - blockIdx.y;          // 128-row q-tile, reversed dispatch
  const int tid  = threadIdx.x;
  const int wave = tid >> 6, lane = tid & 63;
  const int quad = lane >> 4, l15 = lane & 15;
  const int swz  = (l15 & 7) * 8;        // fragment-read XOR (t&7 == l15&7 everywhere used)

  const size_t baseQK = (size_t)bh * T_ * HD_;
  const size_t baseV  = (size_t)bh * HD_ * T_;

  // async staging geometry: 8 chunks of 1024B per 64x64 tile; wave w -> chunks {w, w+4}
  const int ca = wave, cb = wave + 4;
  const bf16* kg_a = Kg + baseQK + ca*512 + (size_t)lane*8;
  const bf16* kg_b = Kg + baseQK + cb*512 + (size_t)lane*8;
  const bf16* vg_a = Vt + baseV + (size_t)(ca*8 + (lane>>3)) * T_ + (lane&7)*8;
  const bf16* vg_b = Vt + baseV + (size_t)(cb*8 + (lane>>3)) * T_ + (lane&7)*8;
  bf16* kl_a0 = &Ks[0][0] + ca*512;  bf16* kl_b0 = &Ks[0][0] + cb*512;
  bf16* vl_a0 = &Vs[0][0] + ca*512;  bf16* vl_b0 = &Vs[0][0] + cb*512;

  // constant ones A-fragment (A[m][k] = (m==0)): denominator row
  bf16x4 ones_f;
  {
    short v = (l15 == 0) ? f2bs(1.0f) : (short)0;
    ones_f = (bf16x4){ v, v, v, v };
  }
  const f32x4 ZV = {0.0f, 0.0f, 0.0f, 0.0f};   // loop-invariant zero C-operand

  // Q fragments -> registers; wave covers q rows qt*128 + s*64 + wave*16 + [0,16)
  bf16x8 qf[2][2];
  #pragma unroll
  for (int s = 0; s < 2; s++){
    const int t = qt*128 + s*64 + wave*16 + l15;
    #pragma unroll
    for (int ks = 0; ks < 2; ks++){
      const int col = (ks*32 + quad*8) ^ swz;
      qf[s][ks] = *reinterpret_cast<const bf16x8*>(Q + baseQK + (size_t)t*HD_ + col);
    }
  }

  // prologue: async tile 0 -> buf 0
  async_load16(kg_a, kl_a0);  async_load16(kg_b, kl_b0);
  async_load16(vg_a, vl_a0);  async_load16(vg_b, vl_b0);

  f32x4 o[2][5] = {};           // per-subtile O^T accum; o[s][4] row0 = softmax denom

  // ---- main loop: j = 0..2qt, both subtiles live; s=1 never masked here ----
  for (int j = 0; j <= 2*qt; j++){
    __syncthreads();   // drains tile-j asyncs (in flight a full iter), publishes LDS

    {  // stage tile j+1 (always exists: j+1 <= 2qt+1 = last tile)
      const int nb = ((j+1) & 1) * 4096;
      const size_t ko = (size_t)(j+1) * 64 * HD_;
      async_load16(kg_a + ko, kl_a0 + nb);  async_load16(kg_b + ko, kl_b0 + nb);
      async_load16(vg_a + (j+1)*64, vl_a0 + nb);
      async_load16(vg_b + (j+1)*64, vl_b0 + nb);
    }

    const bf16* ksb = &Ks[j & 1][0];
    const bf16* vsb = &Vs[j & 1][0];

    // S^T = K * Q^T : tk outer, ks inner; first MFMA takes ZV
    f32x4 st[2][4];
    __builtin_amdgcn_s_setprio(1);
    #pragma unroll
    for (int tk = 0; tk < 4; tk++){
      bf16x8 kf0 = *reinterpret_cast<const bf16x8*>(ksb + (tk*16 + l15)*64 + ((quad*8) ^ swz));
      bf16x8 kf1 = *reinterpret_cast<const bf16x8*>(ksb + (tk*16 + l15)*64 + ((32 + quad*8) ^ swz));
      st[0][tk] = __builtin_amdgcn_mfma_f32_16x16x32_bf16(kf0, qf[0][0], ZV, 0, 0, 0);
      st[1][tk] = __builtin_amdgcn_mfma_f32_16x16x32_bf16(kf0, qf[1][0], ZV, 0, 0, 0);
      st[0][tk] = __builtin_amdgcn_mfma_f32_16x16x32_bf16(kf1, qf[0][1], st[0][tk], 0, 0, 0);
      st[1][tk] = __builtin_amdgcn_mfma_f32_16x16x32_bf16(kf1, qf[1][1], st[1][tk], 0, 0, 0);
    }
    __builtin_amdgcn_s_setprio(0);

    // P = exp2(S); s=0 masked only at the diagonal tile j == 2qt
    bf16x4 pf[2][4];
    {
      const int qg = qt*128 + wave*16 + l15;
      const bool msk = (j == 2*qt);
      #pragma unroll
      for (int tk = 0; tk < 4; tk++){
        float e[4];
        #pragma unroll
        for (int r = 0; r < 4; r++){
          float sv = st[0][tk][r];
          if (msk){
            const int kvg = j*64 + tk*16 + quad*4 + r;
            if (kvg > qg) sv = -1e30f;
          }
          e[r] = fexp2(sv);
        }
        pf[0][tk] = pack_bf16x4(e[0], e[1], e[2], e[3]);
      }
    }
    #pragma unroll
    for (int tk = 0; tk < 4; tk++){
      float e[4];
      #pragma unroll
      for (int r = 0; r < 4; r++) e[r] = fexp2(st[1][tk][r]);
      pf[1][tk] = pack_bf16x4(e[0], e[1], e[2], e[3]);
    }

    // O^T += V^T * P^T ; denom via ones-A-frag
    __builtin_amdgcn_s_setprio(1);
    #pragma unroll
    for (int td = 0; td < 4; td++){
      #pragma unroll
      for (int tk = 0; tk < 4; tk++){
        bf16x4 vf = *reinterpret_cast<const bf16x4*>(vsb + (td*16 + l15)*64 + ((tk*16 + quad*4) ^ swz));
        o[0][td] = __builtin_amdgcn_mfma_f32_16x16x16bf16_1k(vf, pf[0][tk], o[0][td], 0, 0, 0);
        o[1][td] = __builtin_amdgcn_mfma_f32_16x16x16bf16_1k(vf, pf[1][tk], o[1][td], 0, 0, 0);
      }
    }
    #pragma unroll
    for (int tk = 0; tk < 4; tk++){
      o[0][4] = __builtin_amdgcn_mfma_f32_16x16x16bf16_1k(ones_f, pf[0][tk], o[0][4], 0, 0, 0);
      o[1][4] = __builtin_amdgcn_mfma_f32_16x16x16bf16_1k(ones_f, pf[1][tk], o[1][4], 0, 0, 0);
    }
    __builtin_amdgcn_s_setprio(0);
  }

  // ---- peeled last tile j = 2qt+1: subtile 1 only (subtile 0 fully masked -> zeros) ----
  {
    const int j = 2*qt + 1;
    __syncthreads();   // drains the tile staged at main-loop j == 2qt

    const bf16* ksb = &Ks[j & 1][0];
    const bf16* vsb = &Vs[j & 1][0];

    f32x4 st1[4];
    __builtin_amdgcn_s_setprio(1);
    #pragma unroll
    for (int tk = 0; tk < 4; tk++){
      bf16x8 kf0 = *reinterpret_cast<const bf16x8*>(ksb + (tk*16 + l15)*64 + ((quad*8) ^ swz));
      bf16x8 kf1 = *reinterpret_cast<const bf16x8*>(ksb + (tk*16 + l15)*64 + ((32 + quad*8) ^ swz));
      st1[tk] = __builtin_amdgcn_mfma_f32_16x16x32_bf16(kf0, qf[1][0], ZV, 0, 0, 0);
      st1[tk] = __builtin_amdgcn_mfma_f32_16x16x32_bf16(kf1, qf[1][1], st1[tk], 0, 0, 0);
    }
    __builtin_amdgcn_s_setprio(0);

    bf16x4 pf1[4];
    {
      const int qg = qt*128 + 64 + wave*16 + l15;   // subtile-1 rows; diagonal mask
      #pragma unroll
      for (int tk = 0; tk < 4; tk++){
        float e[4];
        #pragma unroll
        for (int r = 0; r < 4; r++){
          float sv = st1[tk][r];
          const int kvg = j*64 + tk*16 + quad*4 + r;
          if (kvg > qg) sv = -1e30f;
          e[r] = fexp2(sv);
        }
        pf1[tk] = pack_bf16x4(e[0], e[1], e[2], e[3]);
      }
    }

    __builtin_amdgcn_s_setprio(1);
    #pragma unroll
    for (int td = 0; td < 4; td++){
      #pragma unroll
      for (int tk = 0; tk < 4; tk++){
        bf16x4 vf = *reinterpret_cast<const bf16x4*>(vsb + (td*16 + l15)*64 + ((tk*16 + quad*4) ^ swz));
        o[1][td] = __builtin_amdgcn_mfma_f32_16x16x16bf16_1k(vf, pf1[tk], o[1][td], 0, 0, 0);
      }
    }
    #pragma unroll
    for (int tk = 0; tk < 4; tk++)
      o[1][4] = __builtin_amdgcn_mfma_f32_16x16x16bf16_1k(ones_f, pf1[tk], o[1][4], 0, 0, 0);
    __builtin_amdgcn_s_setprio(0);
  }

  // normalize + write Y[B*T][C], one 16-row group per wave per subtile
  #pragma unroll
  for (int s = 0; s < 2; s++){
    const float l = __shfl(o[s][4][0], l15, 64);   // quad-0 lane l15 holds q=l15 denom
    const float inv = 1.0f / l;
    const int t = qt*128 + s*64 + wave*16 + l15;
    bf16* yrow = Y + ((size_t)(bb * T_ + t)) * C_ + hh * HD_;
    #pragma unroll
    for (int td = 0; td < 4; td++){
      *reinterpret_cast<bf16x4*>(yrow + td*16 + quad*4) =
        pack_bf16x4(o[s][td][0] * inv, o[s][td][1] * inv,
                    o[s][td][2] * inv, o[s][td][3] * inv);
    }
  }
}

// ---------------- launcher ----------------

extern "C" void kernel_launch(void* const* d_in, const int* in_sizes, int n_in,
                              void* d_out, int out_size, void* d_ws, size_t ws_size,
                              hipStream_t stream) {
  const float* x     = (const float*)d_in[0];
  const float* Wqkv  = (const float*)d_in[1];
  const float* bqkv  = (const float*)d_in[2];
  const float* Wproj = (const float*)d_in[3];
  const float* bproj = (const float*)d_in[4];
  float* out = (float*)d_out;

  const size_t M = (size_t)B_ * T_;
  char* w = (char*)d_ws;
  bf16* xb     = (bf16*)w;  w += M * C_ * 2;
  bf16* WqkvT  = (bf16*)w;  w += (size_t)3 * C_ * C_ * 2;
  bf16* WprojT = (bf16*)w;  w += (size_t)C_ * C_ * 2;
  bf16* Qb     = (bf16*)w;  w += M * C_ * 2;
  bf16* Kb     = (bf16*)w;  w += M * C_ * 2;
  bf16* Vtb    = (bf16*)w;  w += M * C_ * 2;
  bf16* Yb     = (bf16*)w;  w += M * C_ * 2;

  {
    int n = (int)(M * C_);
    k_prep<<<dim3(12288), dim3(256), 0, stream>>>(x, xb, n, Wqkv, WqkvT, Wproj, WprojT);
  }
  k_gemm8<0><<<dim3(M/128, (3*C_)/128), dim3(256), 0, stream>>>(
      xb, WqkvT, bqkv, Qb, Kb, Vtb, nullptr, (int)M, 3*C_, C_);
  k_attn<<<dim3(64, 16), dim3(256), 0, stream>>>(Qb, Kb, Vtb, Yb);
  k_gemm8<1><<<dim3(M/128, C_/128), dim3(256), 0, stream>>>(
      Yb, WprojT, bproj, nullptr, nullptr, nullptr, out, (int)M, C_, C_);
}

// Round 13
// 234.642 us; speedup vs baseline: 1.2479x; 1.0069x over previous
//
#include <hip/hip_runtime.h>
#include <hip/hip_bf16.h>
#include <math.h>

#define B_  4
#define T_  2048
#define C_  1024
#define NH_ 16
#define HD_ 64

using bf16 = __hip_bfloat16;
typedef __attribute__((ext_vector_type(8))) short bf16x8;   // 8 bf16 (4 VGPRs)
typedef __attribute__((ext_vector_type(4))) short bf16x4;   // 4 bf16 (2 VGPRs)
typedef __attribute__((ext_vector_type(4))) float f32x4;

__device__ __forceinline__ bf16 f2b(float f){ return __float2bfloat16(f); }

// fast round-to-nearest-even fp32->bf16 (exact for all finite values; no NaN path)
__device__ __forceinline__ short f2bs(float f){
  union { float f; unsigned u; } x; x.f = f;
  x.u += 0x7FFFu + ((x.u >> 16) & 1u);
  return (short)(x.u >> 16);
}

// packed fp32x2 -> bf16x2 (v_cvt_pk_bf16_f32 on gfx950)
__device__ __forceinline__ bf16x4 pack_bf16x4(float a, float b, float c, float d){
  union { bf16x4 v; __hip_bfloat162 h[2]; } u;
  u.h[0] = __float22bfloat162_rn(make_float2(a, b));
  u.h[1] = __float22bfloat162_rn(make_float2(c, d));
  return u.v;
}

// raw v_exp_f32: exp2 with no ocml range-fixup wrapper.
__device__ __forceinline__ float fexp2(float x){
  float r; asm("v_exp_f32 %0, %1" : "=v"(r) : "v"(x)); return r;
}

__device__ __forceinline__ void async_load16(const bf16* g, bf16* l){
  __builtin_amdgcn_global_load_lds((const __attribute__((address_space(1))) unsigned int*)g,
                                   (__attribute__((address_space(3))) unsigned int*)l,
                                   16, 0, 0);
}

// 0.125 (1/sqrt(64)) * log2(e): softmax runs in exp2 domain
#define QSCALE 0.18033688011112042f

// ---------------- fused prep: x f32->bf16 (blocks 0..8191) + weight transposes ----------------
// ROUND 23: round-12 version (verified best).
__global__ __launch_bounds__(256) void k_prep(const float* __restrict__ x, bf16* __restrict__ xb, int n,
                                              const float* __restrict__ in0, bf16* __restrict__ out0,
                                              const float* __restrict__ in1, bf16* __restrict__ out1){
  __shared__ float t[32][33];
  int b = blockIdx.x;
  if (b < 8192){
    int i = (b * 256 + threadIdx.x) * 4;
    if (i < n){
      float4 f = *(const float4*)(x + i);
      ushort4 u;
      u.x = (unsigned short)f2bs(f.x);
      u.y = (unsigned short)f2bs(f.y);
      u.z = (unsigned short)f2bs(f.z);
      u.w = (unsigned short)f2bs(f.w);
      *(ushort4*)(xb + i) = u;
    }
    return;
  }
  b -= 8192;
  const float* in; bf16* out; int Cc, bx, by;
  if (b < 3072){ in = in0; out = out0; Cc = 3*C_; bx = (b % 96)*32; by = (b / 96)*32; }
  else { b -= 3072; in = in1; out = out1; Cc = C_; bx = (b & 31)*32; by = (b >> 5)*32; }
  const int R = C_;
  int lx = threadIdx.x & 31, ly = threadIdx.x >> 5;
  #pragma unroll
  for (int s = 0; s < 4; s++){
    int k = by + ly + s*8;
    t[ly + s*8][lx] = in[(size_t)k * Cc + bx + lx];
  }
  __syncthreads();
  #pragma unroll
  for (int s = 0; s < 4; s++){
    int n2 = bx + ly + s*8;
    out[(size_t)n2 * R + by + lx] = f2b(t[lx][ly + s*8]);
  }
}

// ------- GEMM0: 256x256 tile, 8 waves (2Mx4N, per-wave 128x64), BK=64 in 4 phases -------
// ROUND 23: faithful port of the guide's verified 8-phase 256^2 structure (m201: 1563 TF,
// 62% MfmaUtil — 2x our gemm8's 742 TF). Key elements: counted vmcnt NEVER 0 in steady
// state, phase-split MFMA clusters between barriers, setprio around MFMA, 128 KB dynamic
// LDS (2 dbuf x 2 k-half x {A 256x32, B 256x32}), 1 block/CU.
// Ledger (verified): stage order per tile = Ak0,Bk0,Ak1,Bk1 (2 loads each, 1 half-matrix
// issued per phase for tile u+1). At tile u ph0: outstanding = u's 8 loads -> vmcnt(4)
// retires exactly Ak0(u),Bk0(u). At ph2: outstanding = {Ak1(u),Bk1(u),Ak0(u+1),Bk0(u+1)}
// -> vmcnt(4) retires Ak1(u),Bk1(u). Last tile ph2: vmcnt(0) (4 outstanding, sole drain).
// Cert: vmcnt -> s_barrier -> ds_read (reads after cross-wave certification). WAR: stages
// into buf e land after ph0 barrier, which all waves pass only after their tile u-1 reads
// fed MFMAs (returned). Swizzle verbatim (row bases 16-aligned -> fsw formula unchanged).
__global__ __launch_bounds__(512) void k_gemm256(
    const bf16* __restrict__ A, const bf16* __restrict__ BT,
    const float* __restrict__ bias,
    bf16* __restrict__ qo, bf16* __restrict__ ko, bf16* __restrict__ vo,
    int M, int N, int K)
{
  extern __shared__ bf16 smem[];          // 128 KB: As[4][8192] then Bs[4][8192]
  bf16* As = smem;
  bf16* Bs = smem + 4*8192;

  const int tid  = threadIdx.x;
  const int wave = tid >> 6, lane = tid & 63;
  const int wm = wave >> 2, wn = wave & 3;      // 2M x 4N; per-wave 128 x 64
  const int quad = lane >> 4, l15 = lane & 15;
  const int bm = blockIdx.x * 256;
  const int bn = blockIdx.y * 256;

  // staging: per half-matrix (256x32) 1024 chunks of 16B; thread covers c = tid, tid+512
  const bf16* gA[2]; const bf16* gB[2]; int lofs[2];
  #pragma unroll
  for (int s = 0; s < 2; s++){
    const int c = tid + s*512;
    const int r = c >> 2, p = (c & 3) ^ ((r >> 1) & 3);
    gA[s] = A  + (size_t)(bm + r)*K + p*8;
    gB[s] = BT + (size_t)(bn + r)*K + p*8;
    lofs[s] = c*8;
  }
  const int fsw = (l15 >> 1) & 3;      // fragment-read chunk XOR

  f32x4 acc[8][4] = {};
  const int S = K >> 6;                // 16 tiles of BK=64

  // prologue: tile 0, order Ak0, Bk0, Ak1, Bk1 (FIFO positions for the counted waits)
  #pragma unroll
  for (int kh = 0; kh < 2; kh++){
    #pragma unroll
    for (int s = 0; s < 2; s++) async_load16(gA[s] + kh*32, As + kh*8192 + lofs[s]);
    #pragma unroll
    for (int s = 0; s < 2; s++) async_load16(gB[s] + kh*32, Bs + kh*8192 + lofs[s]);
  }
  // ^ order emitted: Ak0,Bk0? No: loop emits (A k0, B k0), (A k1, B k1) = Ak0,Bk0,Ak1,Bk1  OK

  for (int u = 0; u < S; u++){
    const int d  = u & 1;
    const int e2 = (d ^ 1) * 2;
    const bf16* a0 = As + (d*2+0)*8192;
    const bf16* a1 = As + (d*2+1)*8192;
    const bf16* b0 = Bs + (d*2+0)*8192;
    const bf16* b1 = Bs + (d*2+1)*8192;
    const bool pre = (u + 1 < S);
    const int off0 = (u + 1) * 64;

    bf16x8 bfv[4], af[4];

    // ---- ph0: certify k0(u); stage Ak0(u+1); compute m0..3 x k0 ----
    asm volatile("s_waitcnt vmcnt(4)" ::: "memory");
    __builtin_amdgcn_s_barrier();
    __builtin_amdgcn_sched_barrier(0);
    if (pre){
      async_load16(gA[0] + off0, As + e2*8192 + lofs[0]);
      async_load16(gA[1] + off0, As + e2*8192 + lofs[1]);
    }
    #pragma unroll
    for (int j = 0; j < 4; j++)
      bfv[j] = *reinterpret_cast<const bf16x8*>(b0 + (wn*64 + j*16 + l15)*32 + ((quad ^ fsw) << 3));
    #pragma unroll
    for (int i = 0; i < 4; i++)
      af[i]  = *reinterpret_cast<const bf16x8*>(a0 + (wm*128 + i*16 + l15)*32 + ((quad ^ fsw) << 3));
    __builtin_amdgcn_s_setprio(1);
    #pragma unroll
    for (int i = 0; i < 4; i++)
      #pragma unroll
      for (int j = 0; j < 4; j++)
        acc[i][j] = __builtin_amdgcn_mfma_f32_16x16x32_bf16(af[i], bfv[j], acc[i][j], 0, 0, 0);
    __builtin_amdgcn_s_setprio(0);

    // ---- ph1: stage Bk0(u+1); compute m4..7 x k0 ----
    if (pre){
      async_load16(gB[0] + off0, Bs + e2*8192 + lofs[0]);
      async_load16(gB[1] + off0, Bs + e2*8192 + lofs[1]);
    }
    #pragma unroll
    for (int i = 0; i < 4; i++)
      af[i]  = *reinterpret_cast<const bf16x8*>(a0 + (wm*128 + 64 + i*16 + l15)*32 + ((quad ^ fsw) << 3));
    __builtin_amdgcn_s_setprio(1);
    #pragma unroll
    for (int i = 0; i < 4; i++)
      #pragma unroll
      for (int j = 0; j < 4; j++)
        acc[4+i][j] = __builtin_amdgcn_mfma_f32_16x16x32_bf16(af[i], bfv[j], acc[4+i][j], 0, 0, 0);
    __builtin_amdgcn_s_setprio(0);

    // ---- ph2: certify k1(u); stage Ak1(u+1); compute m0..3 x k1 ----
    if (pre) asm volatile("s_waitcnt vmcnt(4)" ::: "memory");
    else     asm volatile("s_waitcnt vmcnt(0)" ::: "memory");
    __builtin_amdgcn_s_barrier();
    __builtin_amdgcn_sched_barrier(0);
    if (pre){
      async_load16(gA[0] + off0 + 32, As + (e2+1)*8192 + lofs[0]);
      async_load16(gA[1] + off0 + 32, As + (e2+1)*8192 + lofs[1]);
    }
    #pragma unroll
    for (int j = 0; j < 4; j++)
      bfv[j] = *reinterpret_cast<const bf16x8*>(b1 + (wn*64 + j*16 + l15)*32 + ((quad ^ fsw) << 3));
    #pragma unroll
    for (int i = 0; i < 4; i++)
      af[i]  = *reinterpret_cast<const bf16x8*>(a1 + (wm*128 + i*16 + l15)*32 + ((quad ^ fsw) << 3));
    __builtin_amdgcn_s_setprio(1);
    #pragma unroll
    for (int i = 0; i < 4; i++)
      #pragma unroll
      for (int j = 0; j < 4; j++)
        acc[i][j] = __builtin_amdgcn_mfma_f32_16x16x32_bf16(af[i], bfv[j], acc[i][j], 0, 0, 0);
    __builtin_amdgcn_s_setprio(0);

    // ---- ph3: stage Bk1(u+1); compute m4..7 x k1 ----
    if (pre){
      async_load16(gB[0] + off0 + 32, Bs + (e2+1)*8192 + lofs[0]);
      async_load16(gB[1] + off0 + 32, Bs + (e2+1)*8192 + lofs[1]);
    }
    #pragma unroll
    for (int i = 0; i < 4; i++)
      af[i]  = *reinterpret_cast<const bf16x8*>(a1 + (wm*128 + 64 + i*16 + l15)*32 + ((quad ^ fsw) << 3));
    __builtin_amdgcn_s_setprio(1);
    #pragma unroll
    for (int i = 0; i < 4; i++)
      #pragma unroll
      for (int j = 0; j < 4; j++)
        acc[4+i][j] = __builtin_amdgcn_mfma_f32_16x16x32_bf16(af[i], bfv[j], acc[4+i][j], 0, 0, 0);
    __builtin_amdgcn_s_setprio(0);
  }

  // epilogue: C/D layout row = quad*4 + reg, col = lane&15 (round-8 epilogue, i<8, wm*128)
  {
    const int sec = bn >> 10;
    const int bb2 = bm >> 11;
    const int tb  = (bm & (T_ - 1)) + wm*128 + quad*4;
    const int hn  = ((bn & 1023) >> 6) + wn;
    const size_t bhx = (size_t)(bb2 * NH_ + hn);
    if (sec == 2){
      #pragma unroll
      for (int j = 0; j < 4; j++){
        const int d2 = j*16 + l15;
        const float bj = bias[bn + wn*64 + j*16 + l15];
        bf16* vrow = vo + (bhx * HD_ + d2) * (size_t)T_;
        const int sw = (l15 & 7) * 8;          // kv-swizzle (d&7 == l15&7)
        #pragma unroll
        for (int i = 0; i < 8; i++){
          const int t = (tb + i*16) ^ sw;
          *reinterpret_cast<bf16x4*>(vrow + t) =
            pack_bf16x4(acc[i][j][0] + bj, acc[i][j][1] + bj,
                        acc[i][j][2] + bj, acc[i][j][3] + bj);
        }
      }
    } else {
      bf16* dst = (sec == 0) ? qo : ko;
      const float sc = (sec == 0) ? QSCALE : 1.0f;
      bf16* base = dst + bhx * T_ * HD_;
      float bj[4];
      #pragma unroll
      for (int j = 0; j < 4; j++) bj[j] = bias[bn + wn*64 + j*16 + l15];
      // row-completing order: j innermost -> full 128-B line dirty in consecutive stores
      #pragma unroll
      for (int i = 0; i < 8; i++){
        #pragma unroll
        for (int r = 0; r < 4; r++){
          const int t  = tb + i*16 + r;
          const int sw2 = (t & 7) * 8;
          bf16* prow = base + (size_t)t * HD_;
          #pragma unroll
          for (int j = 0; j < 4; j++){
            const int dq = (j*16 + l15) ^ sw2;   // d-swizzle
            short s = f2bs((acc[i][j][r] + bj[j]) * sc);
            prow[dq] = *(bf16*)&s;
          }
        }
      }
    }
  }
}

// ------- GEMM (proj): 128x128 tile, BK=64 two k-sub-stages, counted-vmcnt (round-8) -------
// ROUND 23: VERBATIM round-8 structure; used for gemm1 only (N=1024 -> 256^2 grid would
// be 128 blocks = half the machine idle at 1 blk/CU).
template<int MODE>
__global__ __launch_bounds__(256, 2) void k_gemm8(
    const bf16* __restrict__ A, const bf16* __restrict__ BT,
    const float* __restrict__ bias,
    bf16* __restrict__ qo, bf16* __restrict__ ko, bf16* __restrict__ vo,
    float* __restrict__ fout,
    int M, int N, int K)
{
  __shared__ bf16 As[2][2][128*32];
  __shared__ bf16 Bs[2][2][128*32];

  const int tid  = threadIdx.x;
  const int wave = tid >> 6, lane = tid & 63;
  const int wm = wave & 1, wn = wave >> 1;          // 2M x 2N wave grid
  const int quad = lane >> 4, l15 = lane & 15;
  const int bm = blockIdx.x * 128;
  const int bn = blockIdx.y * 128;

  const bf16* gA[2]; const bf16* gB[2]; int lofs[2];
  #pragma unroll
  for (int s = 0; s < 2; s++){
    const int c = tid + s*256;
    const int r = c >> 2, p = (c & 3) ^ ((r >> 1) & 3);
    gA[s] = A  + (size_t)(bm + r)*K + p*8;
    gB[s] = BT + (size_t)(bn + r)*K + p*8;
    lofs[s] = c*8;
  }
  const int fsw = (l15 >> 1) & 3;      // fragment-read chunk XOR

  f32x4 acc[4][4] = {};
  const int nT = K >> 6;

  #pragma unroll
  for (int kh = 0; kh < 2; kh++)
    #pragma unroll
    for (int s = 0; s < 2; s++){
      async_load16(gA[s] + kh*32, &As[0][kh][0] + lofs[s]);
      async_load16(gB[s] + kh*32, &Bs[0][kh][0] + lofs[s]);
    }

  for (int u = 0; u < nT; u++){
    const int d = u & 1;
    #pragma unroll
    for (int kh = 0; kh < 2; kh++){
      if (u + 1 < nT || kh == 0) asm volatile("s_waitcnt vmcnt(4)" ::: "memory");
      else                       asm volatile("s_waitcnt vmcnt(0)" ::: "memory");
      __builtin_amdgcn_s_barrier();
      __builtin_amdgcn_sched_barrier(0);

      const bf16* as = &As[d][kh][0];
      const bf16* bs = &Bs[d][kh][0];
      bf16x8 af[4], bfv[4];
      #pragma unroll
      for (int i = 0; i < 4; i++)
        af[i]  = *reinterpret_cast<const bf16x8*>(as + (wm*64 + i*16 + l15)*32 + ((quad ^ fsw) << 3));
      #pragma unroll
      for (int j = 0; j < 4; j++)
        bfv[j] = *reinterpret_cast<const bf16x8*>(bs + (wn*64 + j*16 + l15)*32 + ((quad ^ fsw) << 3));

      if (u + 1 < nT){
        const int ko2 = (u + 1)*64 + kh*32;
        #pragma unroll
        for (int s = 0; s < 2; s++){
          async_load16(gA[s] + ko2, &As[d^1][kh][0] + lofs[s]);
          async_load16(gB[s] + ko2, &Bs[d^1][kh][0] + lofs[s]);
        }
      }

      __builtin_amdgcn_s_setprio(1);
      #pragma unroll
      for (int i = 0; i < 4; i++)
        #pragma unroll
        for (int j = 0; j < 4; j++)
          acc[i][j] = __builtin_amdgcn_mfma_f32_16x16x32_bf16(af[i], bfv[j], acc[i][j], 0, 0, 0);
      __builtin_amdgcn_s_setprio(0);
    }
  }

  if (MODE == 0){
    const int sec = bn >> 10;
    const int bb2 = bm >> 11;
    const int tb  = (bm & (T_ - 1)) + wm*64 + quad*4;
    const int hn  = ((bn & 1023) >> 6) + wn;
    const size_t bhx = (size_t)(bb2 * NH_ + hn);
    if (sec == 2){
      #pragma unroll
      for (int j = 0; j < 4; j++){
        const int d2 = j*16 + l15;
        const float bj = bias[bn + wn*64 + j*16 + l15];
        bf16* vrow = vo + (bhx * HD_ + d2) * (size_t)T_;
        const int sw = (l15 & 7) * 8;
        #pragma unroll
        for (int i = 0; i < 4; i++){
          const int t = (tb + i*16) ^ sw;
          *reinterpret_cast<bf16x4*>(vrow + t) =
            pack_bf16x4(acc[i][j][0] + bj, acc[i][j][1] + bj,
                        acc[i][j][2] + bj, acc[i][j][3] + bj);
        }
      }
    } else {
      bf16* dst = (sec == 0) ? qo : ko;
      const float sc = (sec == 0) ? QSCALE : 1.0f;
      bf16* base = dst + bhx * T_ * HD_;
      float bj[4];
      #pragma unroll
      for (int j = 0; j < 4; j++) bj[j] = bias[bn + wn*64 + j*16 + l15];
      #pragma unroll
      for (int i = 0; i < 4; i++){
        #pragma unroll
        for (int r = 0; r < 4; r++){
          const int t  = tb + i*16 + r;
          const int sw2 = (t & 7) * 8;
          bf16* prow = base + (size_t)t * HD_;
          #pragma unroll
          for (int j = 0; j < 4; j++){
            const int dq = (j*16 + l15) ^ sw2;
            short s = f2bs((acc[i][j][r] + bj[j]) * sc);
            prow[dq] = *(bf16*)&s;
          }
        }
      }
    }
  } else {
    const int n0 = bn + wn*64 + l15;
    float bj[4];
    #pragma unroll
    for (int j = 0; j < 4; j++) bj[j] = bias[n0 + j*16];
    #pragma unroll
    for (int i = 0; i < 4; i++){
      #pragma unroll
      for (int r = 0; r < 4; r++){
        float* p0 = fout + (size_t)(bm + wm*64 + i*16 + quad*4 + r) * N + n0;
        #pragma unroll
        for (int j = 0; j < 4; j++)
          p0[j*16] = acc[i][j][r] + bj[j];
      }
    }
  }
}

// ---------------- flash attention: async dbuf K/V, Q in regs, 128-row q-tiles ----------------
// ROUND 23: round-12 version (verified best; last-tile peel).
__global__ __launch_bounds__(256) void k_attn(
    const bf16* __restrict__ Q, const bf16* __restrict__ Kg,
    const bf16* __restrict__ Vt, bf16* __restrict__ Y)
{
  __shared__ bf16 Ks[2][64*64];   // [kv][d'] unpadded
  __shared__ bf16 Vs[2][64*64];   // [d][kv'] unpadded

  const int bh = blockIdx.x;
  const int bb = bh >> 4, hh = bh & 15;
  const int qt = 15 - blockIdx.y;          // 128-row q-tile, reversed dispatch
  const int tid  = threadIdx.x;
  const int wave = tid >> 6, lane = tid & 63;
  const int quad = lane >> 4, l15 = lane & 15;
  const int swz  = (l15 & 7) * 8;        // fragment-read XOR (t&7 == l15&7 everywhere used)

  const size_t baseQK = (size_t)bh * T_ * HD_;
  const size_t baseV  = (size_t)bh * HD_ * T_;

  const int ca = wave, cb = wave + 4;
  const bf16* kg_a = Kg + baseQK + ca*512 + (size_t)lane*8;
  const bf16* kg_b = Kg + baseQK + cb*512 + (size_t)lane*8;
  const bf16* vg_a = Vt + baseV + (size_t)(ca*8 + (lane>>3)) * T_ + (lane&7)*8;
  const bf16* vg_b = Vt + baseV + (size_t)(cb*8 + (lane>>3)) * T_ + (lane&7)*8;
  bf16* kl_a0 = &Ks[0][0] + ca*512;  bf16* kl_b0 = &Ks[0][0] + cb*512;
  bf16* vl_a0 = &Vs[0][0] + ca*512;  bf16* vl_b0 = &Vs[0][0] + cb*512;

  bf16x4 ones_f;
  {
    short v = (l15 == 0) ? f2bs(1.0f) : (short)0;
    ones_f = (bf16x4){ v, v, v, v };
  }
  const f32x4 ZV = {0.0f, 0.0f, 0.0f, 0.0f};

  bf16x8 qf[2][2];
  #pragma unroll
  for (int s = 0; s < 2; s++){
    const int t = qt*128 + s*64 + wave*16 + l15;
    #pragma unroll
    for (int ks = 0; ks < 2; ks++){
      const int col = (ks*32 + quad*8) ^ swz;
      qf[s][ks] = *reinterpret_cast<const bf16x8*>(Q + baseQK + (size_t)t*HD_ + col);
    }
  }

  async_load16(kg_a, kl_a0);  async_load16(kg_b, kl_b0);
  async_load16(vg_a, vl_a0);  async_load16(vg_b, vl_b0);

  f32x4 o[2][5] = {};

  for (int j = 0; j <= 2*qt; j++){
    __syncthreads();

    {
      const int nb = ((j+1) & 1) * 4096;
      const size_t ko = (size_t)(j+1) * 64 * HD_;
      async_load16(kg_a + ko, kl_a0 + nb);  async_load16(kg_b + ko, kl_b0 + nb);
      async_load16(vg_a + (j+1)*64, vl_a0 + nb);
      async_load16(vg_b + (j+1)*64, vl_b0 + nb);
    }

    const bf16* ksb = &Ks[j & 1][0];
    const bf16* vsb = &Vs[j & 1][0];

    f32x4 st[2][4];
    __builtin_amdgcn_s_setprio(1);
    #pragma unroll
    for (int tk = 0; tk < 4; tk++){
      bf16x8 kf0 = *reinterpret_cast<const bf16x8*>(ksb + (tk*16 + l15)*64 + ((quad*8) ^ swz));
      bf16x8 kf1 = *reinterpret_cast<const bf16x8*>(ksb + (tk*16 + l15)*64 + ((32 + quad*8) ^ swz));
      st[0][tk] = __builtin_amdgcn_mfma_f32_16x16x32_bf16(kf0, qf[0][0], ZV, 0, 0, 0);
      st[1][tk] = __builtin_amdgcn_mfma_f32_16x16x32_bf16(kf0, qf[1][0], ZV, 0, 0, 0);
      st[0][tk] = __builtin_amdgcn_mfma_f32_16x16x32_bf16(kf1, qf[0][1], st[0][tk], 0, 0, 0);
      st[1][tk] = __builtin_amdgcn_mfma_f32_16x16x32_bf16(kf1, qf[1][1], st[1][tk], 0, 0, 0);
    }
    __builtin_amdgcn_s_setprio(0);

    bf16x4 pf[2][4];
    {
      const int qg = qt*128 + wave*16 + l15;
      const bool msk = (j == 2*qt);
      #pragma unroll
      for (int tk = 0; tk < 4; tk++){
        float e[4];
        #pragma unroll
        for (int r = 0; r < 4; r++){
          float sv = st[0][tk][r];
          if (msk){
            const int kvg = j*64 + tk*16 + quad*4 + r;
            if (kvg > qg) sv = -1e30f;
          }
          e[r] = fexp2(sv);
        }
        pf[0][tk] = pack_bf16x4(e[0], e[1], e[2], e[3]);
      }
    }
    #pragma unroll
    for (int tk = 0; tk < 4; tk++){
      float e[4];
      #pragma unroll
      for (int r = 0; r < 4; r++) e[r] = fexp2(st[1][tk][r]);
      pf[1][tk] = pack_bf16x4(e[0], e[1], e[2], e[3]);
    }

    __builtin_amdgcn_s_setprio(1);
    #pragma unroll
    for (int td = 0; td < 4; td++){
      #pragma unroll
      for (int tk = 0; tk < 4; tk++){
        bf16x4 vf = *reinterpret_cast<const bf16x4*>(vsb + (td*16 + l15)*64 + ((tk*16 + quad*4) ^ swz));
        o[0][td] = __builtin_amdgcn_mfma_f32_16x16x16bf16_1k(vf, pf[0][tk], o[0][td], 0, 0, 0);
        o[1][td] = __builtin_amdgcn_mfma_f32_16x16x16bf16_1k(vf, pf[1][tk], o[1][td], 0, 0, 0);
      }
    }
    #pragma unroll
    for (int tk = 0; tk < 4; tk++){
      o[0][4] = __builtin_amdgcn_mfma_f32_16x16x16bf16_1k(ones_f, pf[0][tk], o[0][4], 0, 0, 0);
      o[1][4] = __builtin_amdgcn_mfma_f32_16x16x16bf16_1k(ones_f, pf[1][tk], o[1][4], 0, 0, 0);
    }
    __builtin_amdgcn_s_setprio(0);
  }

  {
    const int j = 2*qt + 1;
    __syncthreads();

    const bf16* ksb = &Ks[j & 1][0];
    const bf16* vsb = &Vs[j & 1][0];

    f32x4 st1[4];
    __builtin_amdgcn_s_setprio(1);
    #pragma unroll
    for (int tk = 0; tk < 4; tk++){
      bf16x8 kf0 = *reinterpret_cast<const bf16x8*>(ksb + (tk*16 + l15)*64 + ((quad*8) ^ swz));
      bf16x8 kf1 = *reinterpret_cast<const bf16x8*>(ksb + (tk*16 + l15)*64 + ((32 + quad*8) ^ swz));
      st1[tk] = __builtin_amdgcn_mfma_f32_16x16x32_bf16(kf0, qf[1][0], ZV, 0, 0, 0);
      st1[tk] = __builtin_amdgcn_mfma_f32_16x16x32_bf16(kf1, qf[1][1], st1[tk], 0, 0, 0);
    }
    __builtin_amdgcn_s_setprio(0);

    bf16x4 pf1[4];
    {
      const int qg = qt*128 + 64 + wave*16 + l15;
      #pragma unroll
      for (int tk = 0; tk < 4; tk++){
        float e[4];
        #pragma unroll
        for (int r = 0; r < 4; r++){
          float sv = st1[tk][r];
          const int kvg = j*64 + tk*16 + quad*4 + r;
          if (kvg > qg) sv = -1e30f;
          e[r] = fexp2(sv);
        }
        pf1[tk] = pack_bf16x4(e[0], e[1], e[2], e[3]);
      }
    }

    __builtin_amdgcn_s_setprio(1);
    #pragma unroll
    for (int td = 0; td < 4; td++){
      #pragma unroll
      for (int tk = 0; tk < 4; tk++){
        bf16x4 vf = *reinterpret_cast<const bf16x4*>(vsb + (td*16 + l15)*64 + ((tk*16 + quad*4) ^ swz));
        o[1][td] = __builtin_amdgcn_mfma_f32_16x16x16bf16_1k(vf, pf1[tk], o[1][td], 0, 0, 0);
      }
    }
    #pragma unroll
    for (int tk = 0; tk < 4; tk++)
      o[1][4] = __builtin_amdgcn_mfma_f32_16x16x16bf16_1k(ones_f, pf1[tk], o[1][4], 0, 0, 0);
    __builtin_amdgcn_s_setprio(0);
  }

  #pragma unroll
  for (int s = 0; s < 2; s++){
    const float l = __shfl(o[s][4][0], l15, 64);
    const float inv = 1.0f / l;
    const int t = qt*128 + s*64 + wave*16 + l15;
    bf16* yrow = Y + ((size_t)(bb * T_ + t)) * C_ + hh * HD_;
    #pragma unroll
    for (int td = 0; td < 4; td++){
      *reinterpret_cast<bf16x4*>(yrow + td*16 + quad*4) =
        pack_bf16x4(o[s][td][0] * inv, o[s][td][1] * inv,
                    o[s][td][2] * inv, o[s][td][3] * inv);
    }
  }
}

// ---------------- launcher ----------------

extern "C" void kernel_launch(void* const* d_in, const int* in_sizes, int n_in,
                              void* d_out, int out_size, void* d_ws, size_t ws_size,
                              hipStream_t stream) {
  const float* x     = (const float*)d_in[0];
  const float* Wqkv  = (const float*)d_in[1];
  const float* bqkv  = (const float*)d_in[2];
  const float* Wproj = (const float*)d_in[3];
  const float* bproj = (const float*)d_in[4];
  float* out = (float*)d_out;

  const size_t M = (size_t)B_ * T_;
  char* w = (char*)d_ws;
  bf16* xb     = (bf16*)w;  w += M * C_ * 2;
  bf16* WqkvT  = (bf16*)w;  w += (size_t)3 * C_ * C_ * 2;
  bf16* WprojT = (bf16*)w;  w += (size_t)C_ * C_ * 2;
  bf16* Qb     = (bf16*)w;  w += M * C_ * 2;
  bf16* Kb     = (bf16*)w;  w += M * C_ * 2;
  bf16* Vtb    = (bf16*)w;  w += M * C_ * 2;
  bf16* Yb     = (bf16*)w;  w += M * C_ * 2;

  // one-time opt-in for 128 KB dynamic LDS on k_gemm256 (host-side, not a stream op)
  static bool attr_done = false;
  if (!attr_done){
    hipFuncSetAttribute(reinterpret_cast<const void*>(k_gemm256),
                        hipFuncAttributeMaxDynamicSharedMemorySize, 131072);
    attr_done = true;
  }

  {
    int n = (int)(M * C_);
    k_prep<<<dim3(12288), dim3(256), 0, stream>>>(x, xb, n, Wqkv, WqkvT, Wproj, WprojT);
  }
  k_gemm256<<<dim3(M/256, (3*C_)/256), dim3(512), 131072, stream>>>(
      xb, WqkvT, bqkv, Qb, Kb, Vtb, (int)M, 3*C_, C_);
  k_attn<<<dim3(64, 16), dim3(256), 0, stream>>>(Qb, Kb, Vtb, Yb);
  k_gemm8<1><<<dim3(M/128, C_/128), dim3(256), 0, stream>>>(
      Yb, WprojT, bproj, nullptr, nullptr, nullptr, out, (int)M, C_, C_);
}